// Round 1
// baseline (3852.865 us; speedup 1.0000x reference)
//
#include <hip/hip_runtime.h>
#include <hip/hip_bf16.h>
#include <float.h>
#include <stdint.h>

#define NEG_SLOPE 0.2f

// ---------------------------------------------------------------------------
// edge_index may arrive as int32 or int64 (reference declares int64, but JAX
// x64-default / harness conversion is ambiguous). Detect on device: int64
// values < 50000 => every odd 32-bit word is zero.
// ---------------------------------------------------------------------------
__global__ void detect_idx64_kernel(const void* ei, int* flag) {
  if (threadIdx.x == 0 && blockIdx.x == 0) {
    const int* p = (const int*)ei;
    int allz = 1;
    for (int j = 1; j < 128; j += 2) {
      if (p[j] != 0) { allz = 0; break; }
    }
    *flag = allz;
  }
}

__device__ inline int load_idx(const void* ei, long long pos, int is64) {
  if (is64) return (int)((const long long*)ei)[pos];
  return ((const int*)ei)[pos];
}

// ---------------------------------------------------------------------------
// fp32 GEMM: C[M,N] = A[M,K] * B[K,N], row-major. 64x64 block tile, 16x16
// threads, 4x4 micro-tile, K-tile 16. Correct-first; optimize later.
// ---------------------------------------------------------------------------
__global__ __launch_bounds__(256) void gemm_f32(
    const float* __restrict__ A, const float* __restrict__ B,
    float* __restrict__ C, int M, int N, int K) {
  __shared__ float As[16][68];  // [k][m], row stride 68 floats (16B aligned, pad)
  __shared__ float Bs[16][64];  // [k][n]
  const int bm = blockIdx.x * 64;
  const int bn = blockIdx.y * 64;
  const int tid = threadIdx.x;
  const int tx = tid & 15, ty = tid >> 4;
  float acc[4][4] = {};
  for (int k0 = 0; k0 < K; k0 += 16) {
    {  // stage A: 64 rows x 16 k
      const int c = tid & 15;
      const int r0 = tid >> 4;
#pragma unroll
      for (int i = 0; i < 4; ++i) {
        int r = r0 + i * 16;
        int gm = bm + r;
        As[c][r] = (gm < M) ? A[(long long)gm * K + k0 + c] : 0.f;
      }
    }
    {  // stage B: 16 k x 64 n
      const int n = tid & 63;
      const int kb = tid >> 6;  // 0..3
#pragma unroll
      for (int i = 0; i < 4; ++i) {
        int kk = kb + i * 4;
        Bs[kk][n] = B[(long long)(k0 + kk) * N + bn + n];
      }
    }
    __syncthreads();
#pragma unroll
    for (int kk = 0; kk < 16; ++kk) {
      float4 a4 = *(const float4*)&As[kk][ty * 4];
      float4 b4 = *(const float4*)&Bs[kk][tx * 4];
      float a[4] = {a4.x, a4.y, a4.z, a4.w};
      float b[4] = {b4.x, b4.y, b4.z, b4.w};
#pragma unroll
      for (int i = 0; i < 4; ++i)
#pragma unroll
        for (int j = 0; j < 4; ++j) acc[i][j] += a[i] * b[j];
    }
    __syncthreads();
  }
#pragma unroll
  for (int i = 0; i < 4; ++i) {
    int gm = bm + ty * 4 + i;
    if (gm < M) {
      float* crow = C + (long long)gm * N + bn + tx * 4;
      crow[0] = acc[i][0]; crow[1] = acc[i][1];
      crow[2] = acc[i][2]; crow[3] = acc[i][3];
    }
  }
}

// ---------------------------------------------------------------------------
// Per-node attention scores: as[i] = h[i,:]·a_src, ad[i] = h[i,:]·a_dst.
// One wave per node.
// ---------------------------------------------------------------------------
__global__ __launch_bounds__(256) void alpha_kernel(
    const float* __restrict__ h, const float* __restrict__ a_src,
    const float* __restrict__ a_dst, float* __restrict__ as_out,
    float* __restrict__ ad_out, int Nn, int F) {
  int wave = (int)(((long long)blockIdx.x * blockDim.x + threadIdx.x) >> 6);
  int lane = threadIdx.x & 63;
  if (wave >= Nn) return;
  const float* row = h + (long long)wave * F;
  float s1 = 0.f, s2 = 0.f;
  for (int f = lane; f < F; f += 64) {
    float v = row[f];
    s1 += v * a_src[f];
    s2 += v * a_dst[f];
  }
#pragma unroll
  for (int off = 32; off > 0; off >>= 1) {
    s1 += __shfl_down(s1, off);
    s2 += __shfl_down(s2, off);
  }
  if (lane == 0) {
    as_out[wave] = s1;
    ad_out[wave] = s2;
  }
}

// float <-> order-preserving uint key (for atomicMax on floats)
__device__ inline unsigned int f2key(float f) {
  unsigned int b = __float_as_uint(f);
  return (b & 0x80000000u) ? ~b : (b | 0x80000000u);
}
__device__ inline float key2f(unsigned int k) {
  unsigned int b = (k & 0x80000000u) ? (k & 0x7FFFFFFFu) : ~k;
  return __uint_as_float(b);
}

// pass 1: per-edge logit e = leaky_relu(as[src]+ad[dst]); atomicMax emax[dst]
__global__ __launch_bounds__(256) void edge_logits(
    const void* __restrict__ ei, const int* __restrict__ flag64, int E, int Nn,
    const float* __restrict__ as, const float* __restrict__ ad,
    float* __restrict__ e_out, unsigned int* __restrict__ emax_key) {
  const int is64 = *flag64;
  int j = blockIdx.x * blockDim.x + threadIdx.x;
  const int NE = E + Nn;
  if (j >= NE) return;
  int s, d;
  if (j < E) {
    s = load_idx(ei, j, is64);
    d = load_idx(ei, (long long)E + j, is64);
  } else {
    s = d = j - E;
  }
  float e = as[s] + ad[d];
  e = (e >= 0.f) ? e : NEG_SLOPE * e;
  e_out[j] = e;
  atomicMax(&emax_key[d], f2key(e));
}

// pass 2: p = exp(e - emax[dst]); atomicAdd denom[dst]
__global__ __launch_bounds__(256) void edge_denom(
    const void* __restrict__ ei, const int* __restrict__ flag64, int E, int Nn,
    const float* __restrict__ e_in, const unsigned int* __restrict__ emax_key,
    float* __restrict__ denom) {
  const int is64 = *flag64;
  int j = blockIdx.x * blockDim.x + threadIdx.x;
  const int NE = E + Nn;
  if (j >= NE) return;
  int d = (j < E) ? load_idx(ei, (long long)E + j, is64) : (j - E);
  float p = __expf(e_in[j] - key2f(emax_key[d]));
  atomicAdd(&denom[d], p);
}

// pass 3: one wave per edge; out[dst,:] += alpha * h[src,:]
template <int F>
__global__ __launch_bounds__(256) void edge_scatter(
    const void* __restrict__ ei, const int* __restrict__ flag64, int E, int Nn,
    const float* __restrict__ e_in, const unsigned int* __restrict__ emax_key,
    const float* __restrict__ denom, const float* __restrict__ h,
    float* __restrict__ outp) {
  const int is64 = *flag64;
  int gwave = (int)(((long long)blockIdx.x * blockDim.x + threadIdx.x) >> 6);
  int lane = threadIdx.x & 63;
  const int NE = E + Nn;
  if (gwave >= NE) return;
  int j = gwave;
  int s, d;
  if (j < E) {
    s = load_idx(ei, j, is64);
    d = load_idx(ei, (long long)E + j, is64);
  } else {
    s = d = j - E;
  }
  float alpha = __expf(e_in[j] - key2f(emax_key[d])) / (denom[d] + 1e-16f);
  const float* hrow = h + (long long)s * F;
  float* orow = outp + (long long)d * F;
  if (F == 256) {
    int f = lane * 4;
    float4 v = *(const float4*)(hrow + f);
    atomicAdd(&orow[f + 0], alpha * v.x);
    atomicAdd(&orow[f + 1], alpha * v.y);
    atomicAdd(&orow[f + 2], alpha * v.z);
    atomicAdd(&orow[f + 3], alpha * v.w);
  } else {  // F == 128
    int f = lane * 2;
    float2 v = *(const float2*)(hrow + f);
    atomicAdd(&orow[f + 0], alpha * v.x);
    atomicAdd(&orow[f + 1], alpha * v.y);
  }
}

// out = relu(out + b)  (b broadcast over feature dim F, F power of two)
__global__ __launch_bounds__(256) void bias_relu(
    float* __restrict__ xo, const float* __restrict__ b, long long n, int F) {
  long long i = (long long)blockIdx.x * blockDim.x + threadIdx.x;
  long long stride = (long long)gridDim.x * blockDim.x;
  for (; i < n; i += stride) {
    float v = xo[i] + b[(int)(i & (F - 1))];
    xo[i] = v > 0.f ? v : 0.f;
  }
}

extern "C" void kernel_launch(void* const* d_in, const int* in_sizes, int n_in,
                              void* d_out, int out_size, void* d_ws,
                              size_t ws_size, hipStream_t stream) {
  const float* x      = (const float*)d_in[0];
  const void*  ei     = d_in[1];
  const float* W1     = (const float*)d_in[2];
  const float* a1_src = (const float*)d_in[3];
  const float* a1_dst = (const float*)d_in[4];
  const float* b1     = (const float*)d_in[5];
  const float* W2     = (const float*)d_in[6];
  const float* a2_src = (const float*)d_in[7];
  const float* a2_dst = (const float*)d_in[8];
  const float* b2     = (const float*)d_in[9];
  float* out = (float*)d_out;

  const int N = 50000, E = 800000, IN = 128, HID = 256, OUT = 128;
  const int NE = E + N;

  // ---- workspace carve (all 256B aligned) ----
  char* ws = (char*)d_ws;
  size_t off = 0;
  auto carve = [&](size_t bytes) -> void* {
    void* p = ws + off;
    off = (off + bytes + 255) & ~(size_t)255;
    return p;
  };
  float* h    = (float*)carve((size_t)N * HID * 4);  // h1, reused as h2
  float* out1 = (float*)carve((size_t)N * HID * 4);  // layer-1 aggregate
  float* ee   = (float*)carve((size_t)NE * 4);       // per-edge logits
  float* smalls = (float*)carve((size_t)8 * N * 4);  // 8 per-node arrays
  float*        as1   = smalls + 0 * N;
  float*        ad1   = smalls + 1 * N;
  unsigned int* emax1 = (unsigned int*)(smalls + 2 * N);
  float*        den1  = smalls + 3 * N;
  float*        as2   = smalls + 4 * N;
  float*        ad2   = smalls + 5 * N;
  unsigned int* emax2 = (unsigned int*)(smalls + 6 * N);
  float*        den2  = smalls + 7 * N;
  int* flag64 = (int*)carve(256);
  (void)ws_size; (void)in_sizes; (void)n_in;

  // ---- zero-init accumulators (emax key 0 == -NaN sentinel, always beaten) ----
  hipMemsetAsync(out1, 0, (size_t)N * HID * 4, stream);
  hipMemsetAsync(out, 0, (size_t)out_size * 4, stream);
  hipMemsetAsync(smalls, 0, (size_t)8 * N * 4, stream);

  detect_idx64_kernel<<<1, 64, 0, stream>>>(ei, flag64);

  const int eb = (NE + 255) / 256;        // per-edge thread kernels
  const int sb = (NE + 3) / 4;            // wave-per-edge kernels (4 waves/block)
  const int ab = (N * 64 + 255) / 256;    // wave-per-node kernels

  // ---- layer 1: x[ N,128 ] -> out1[ N,256 ] ----
  {
    dim3 g((N + 63) / 64, HID / 64);
    gemm_f32<<<g, 256, 0, stream>>>(x, W1, h, N, HID, IN);
  }
  alpha_kernel<<<ab, 256, 0, stream>>>(h, a1_src, a1_dst, as1, ad1, N, HID);
  edge_logits<<<eb, 256, 0, stream>>>(ei, flag64, E, N, as1, ad1, ee, emax1);
  edge_denom<<<eb, 256, 0, stream>>>(ei, flag64, E, N, ee, emax1, den1);
  edge_scatter<256><<<sb, 256, 0, stream>>>(ei, flag64, E, N, ee, emax1, den1, h, out1);
  bias_relu<<<2048, 256, 0, stream>>>(out1, b1, (long long)N * HID, HID);

  // ---- layer 2: out1[ N,256 ] -> out[ N,128 ] ----
  {
    dim3 g((N + 63) / 64, OUT / 64);
    gemm_f32<<<g, 256, 0, stream>>>(out1, W2, h, N, OUT, HID);
  }
  alpha_kernel<<<ab, 256, 0, stream>>>(h, a2_src, a2_dst, as2, ad2, N, OUT);
  edge_logits<<<eb, 256, 0, stream>>>(ei, flag64, E, N, as2, ad2, ee, emax2);
  edge_denom<<<eb, 256, 0, stream>>>(ei, flag64, E, N, ee, emax2, den2);
  edge_scatter<128><<<sb, 256, 0, stream>>>(ei, flag64, E, N, ee, emax2, den2, h, out);
  bias_relu<<<2048, 256, 0, stream>>>(out, b2, (long long)N * OUT, OUT);
}

// Round 2
// 469.234 us; speedup vs baseline: 8.2110x; 8.2110x over previous
//
#include <hip/hip_runtime.h>
#include <hip/hip_bf16.h>
#include <float.h>
#include <stdint.h>

#define NEG_SLOPE 0.2f

// ---------------------------------------------------------------------------
// edge_index may arrive as int32 or int64. Detect on device: int64 values
// < 50000 => every odd 32-bit word is zero.
// ---------------------------------------------------------------------------
__global__ void detect_idx64_kernel(const void* ei, int* flag) {
  if (threadIdx.x == 0 && blockIdx.x == 0) {
    const int* p = (const int*)ei;
    int allz = 1;
    for (int j = 1; j < 128; j += 2) {
      if (p[j] != 0) { allz = 0; break; }
    }
    *flag = allz;
  }
}

__device__ inline int load_idx(const void* ei, long long pos, int is64) {
  if (is64) return (int)((const long long*)ei)[pos];
  return ((const int*)ei)[pos];
}

__device__ inline float leaky(float e) { return e >= 0.f ? e : NEG_SLOPE * e; }

// ---------------------------------------------------------------------------
// CSR build: deg histogram -> 3-kernel exclusive scan -> placement scatter.
// ---------------------------------------------------------------------------
__global__ __launch_bounds__(256) void hist_kernel(
    const void* __restrict__ ei, const int* __restrict__ flag64, int E,
    int* __restrict__ deg) {
  const int is64 = *flag64;
  int j = blockIdx.x * blockDim.x + threadIdx.x;
  if (j >= E) return;
  int d = load_idx(ei, (long long)E + j, is64);
  atomicAdd(&deg[d], 1);
}

// blocks of 1024 elements, 256 threads x 4 sequential each
__global__ __launch_bounds__(256) void scan1(
    const int* __restrict__ deg, int* __restrict__ rowstart,
    int* __restrict__ bsum, int n) {
  __shared__ int tsum[256];
  const int base = blockIdx.x * 1024;
  const int t = threadIdx.x;
  int vals[4];
  int s = 0;
#pragma unroll
  for (int i = 0; i < 4; ++i) {
    int idx = base + t * 4 + i;
    vals[i] = (idx < n) ? deg[idx] : 0;
    s += vals[i];
  }
  tsum[t] = s;
  __syncthreads();
  // inclusive Hillis-Steele over thread sums
  for (int off = 1; off < 256; off <<= 1) {
    int v = (t >= off) ? tsum[t - off] : 0;
    __syncthreads();
    tsum[t] += v;
    __syncthreads();
  }
  int excl = (t > 0) ? tsum[t - 1] : 0;
#pragma unroll
  for (int i = 0; i < 4; ++i) {
    int idx = base + t * 4 + i;
    if (idx < n) rowstart[idx] = excl;
    excl += vals[i];
  }
  if (t == 255) bsum[blockIdx.x] = tsum[255];
}

__global__ void scan2(int* bsum, int nb) {
  if (threadIdx.x == 0 && blockIdx.x == 0) {
    int run = 0;
    for (int i = 0; i < nb; ++i) {
      int v = bsum[i];
      bsum[i] = run;
      run += v;
    }
  }
}

__global__ __launch_bounds__(256) void scan3(
    int* __restrict__ rowstart, const int* __restrict__ bsum,
    int* __restrict__ cursor, int n, int Etot) {
  int i = blockIdx.x * blockDim.x + threadIdx.x;
  if (i < n) {
    int v = rowstart[i] + bsum[i >> 10];
    rowstart[i] = v;
    cursor[i] = v;
  } else if (i == n) {
    rowstart[n] = Etot;
  }
}

__global__ __launch_bounds__(256) void csr_place(
    const void* __restrict__ ei, const int* __restrict__ flag64, int E,
    int* __restrict__ cursor, int* __restrict__ csr_src) {
  const int is64 = *flag64;
  int j = blockIdx.x * blockDim.x + threadIdx.x;
  if (j >= E) return;
  int s = load_idx(ei, j, is64);
  int d = load_idx(ei, (long long)E + j, is64);
  int pos = atomicAdd(&cursor[d], 1);
  csr_src[pos] = s;
}

// ---------------------------------------------------------------------------
// fp32 GEMM: C[M,N] = A[M,K] * B[K,N], row-major. 64x64 tile, 4x4 micro.
// ---------------------------------------------------------------------------
__global__ __launch_bounds__(256) void gemm_f32(
    const float* __restrict__ A, const float* __restrict__ B,
    float* __restrict__ C, int M, int N, int K) {
  __shared__ float As[16][68];
  __shared__ float Bs[16][64];
  const int bm = blockIdx.x * 64;
  const int bn = blockIdx.y * 64;
  const int tid = threadIdx.x;
  const int tx = tid & 15, ty = tid >> 4;
  float acc[4][4] = {};
  for (int k0 = 0; k0 < K; k0 += 16) {
    {
      const int c = tid & 15;
      const int r0 = tid >> 4;
#pragma unroll
      for (int i = 0; i < 4; ++i) {
        int r = r0 + i * 16;
        int gm = bm + r;
        As[c][r] = (gm < M) ? A[(long long)gm * K + k0 + c] : 0.f;
      }
    }
    {
      const int n = tid & 63;
      const int kb = tid >> 6;
#pragma unroll
      for (int i = 0; i < 4; ++i) {
        int kk = kb + i * 4;
        Bs[kk][n] = B[(long long)(k0 + kk) * N + bn + n];
      }
    }
    __syncthreads();
#pragma unroll
    for (int kk = 0; kk < 16; ++kk) {
      float4 a4 = *(const float4*)&As[kk][ty * 4];
      float4 b4 = *(const float4*)&Bs[kk][tx * 4];
      float a[4] = {a4.x, a4.y, a4.z, a4.w};
      float b[4] = {b4.x, b4.y, b4.z, b4.w};
#pragma unroll
      for (int i = 0; i < 4; ++i)
#pragma unroll
        for (int j = 0; j < 4; ++j) acc[i][j] += a[i] * b[j];
    }
    __syncthreads();
  }
#pragma unroll
  for (int i = 0; i < 4; ++i) {
    int gm = bm + ty * 4 + i;
    if (gm < M) {
      float* crow = C + (long long)gm * N + bn + tx * 4;
      crow[0] = acc[i][0]; crow[1] = acc[i][1];
      crow[2] = acc[i][2]; crow[3] = acc[i][3];
    }
  }
}

// ---------------------------------------------------------------------------
// Per-node attention scores: as[i] = h[i,:]·a_src, ad[i] = h[i,:]·a_dst.
// ---------------------------------------------------------------------------
__global__ __launch_bounds__(256) void alpha_kernel(
    const float* __restrict__ h, const float* __restrict__ a_src,
    const float* __restrict__ a_dst, float* __restrict__ as_out,
    float* __restrict__ ad_out, int Nn, int F) {
  int wave = (int)(((long long)blockIdx.x * blockDim.x + threadIdx.x) >> 6);
  int lane = threadIdx.x & 63;
  if (wave >= Nn) return;
  const float* row = h + (long long)wave * F;
  float s1 = 0.f, s2 = 0.f;
  for (int f = lane; f < F; f += 64) {
    float v = row[f];
    s1 += v * a_src[f];
    s2 += v * a_dst[f];
  }
#pragma unroll
  for (int off = 32; off > 0; off >>= 1) {
    s1 += __shfl_down(s1, off);
    s2 += __shfl_down(s2, off);
  }
  if (lane == 0) {
    as_out[wave] = s1;
    ad_out[wave] = s2;
  }
}

// ---------------------------------------------------------------------------
// Fused per-dst-node softmax + gather-aggregate + bias + ReLU.
// One wave per node. Self-loop handled implicitly (not stored in CSR).
// F=256: lane holds float4; F=128: lane holds float2.
// ---------------------------------------------------------------------------
template <int F>
__global__ __launch_bounds__(256) void gat_aggregate(
    const int* __restrict__ rowstart, const int* __restrict__ csr_src,
    const float* __restrict__ as, const float* __restrict__ ad,
    const float* __restrict__ h, const float* __restrict__ bias,
    float* __restrict__ outp, int Nn) {
  int node = blockIdx.x * (blockDim.x >> 6) + (threadIdx.x >> 6);
  int lane = threadIdx.x & 63;
  if (node >= Nn) return;
  const int beg = rowstart[node];
  const int end = rowstart[node + 1];
  const float adn = ad[node];
  const float e_self = leaky(as[node] + adn);

  // phase A: wave-parallel max over edges (+ self-loop)
  float m = e_self;
  for (int t = beg + lane; t < end; t += 64)
    m = fmaxf(m, leaky(as[csr_src[t]] + adn));
#pragma unroll
  for (int off = 32; off > 0; off >>= 1) m = fmaxf(m, __shfl_xor(m, off));

  // phase A2: wave-parallel denom
  float dsum = 0.f;
  for (int t = beg + lane; t < end; t += 64)
    dsum += __expf(leaky(as[csr_src[t]] + adn) - m);
#pragma unroll
  for (int off = 32; off > 0; off >>= 1) dsum += __shfl_xor(dsum, off);
  const float inv = 1.f / (dsum + __expf(e_self - m) + 1e-16f);

  // phase B: sequential over edges, lane-parallel over features
  if (F == 256) {
    const int f = lane * 4;
    float4 acc;
    {
      float a0 = __expf(e_self - m) * inv;
      float4 v = *(const float4*)(h + (long long)node * F + f);
      acc.x = a0 * v.x; acc.y = a0 * v.y; acc.z = a0 * v.z; acc.w = a0 * v.w;
    }
    for (int t = beg; t < end; ++t) {
      int s = csr_src[t];
      float al = __expf(leaky(as[s] + adn) - m) * inv;
      float4 v = *(const float4*)(h + (long long)s * F + f);
      acc.x += al * v.x; acc.y += al * v.y; acc.z += al * v.z; acc.w += al * v.w;
    }
    acc.x = fmaxf(acc.x + bias[f + 0], 0.f);
    acc.y = fmaxf(acc.y + bias[f + 1], 0.f);
    acc.z = fmaxf(acc.z + bias[f + 2], 0.f);
    acc.w = fmaxf(acc.w + bias[f + 3], 0.f);
    *(float4*)(outp + (long long)node * F + f) = acc;
  } else {
    const int f = lane * 2;
    float2 acc;
    {
      float a0 = __expf(e_self - m) * inv;
      float2 v = *(const float2*)(h + (long long)node * F + f);
      acc.x = a0 * v.x; acc.y = a0 * v.y;
    }
    for (int t = beg; t < end; ++t) {
      int s = csr_src[t];
      float al = __expf(leaky(as[s] + adn) - m) * inv;
      float2 v = *(const float2*)(h + (long long)s * F + f);
      acc.x += al * v.x; acc.y += al * v.y;
    }
    acc.x = fmaxf(acc.x + bias[f + 0], 0.f);
    acc.y = fmaxf(acc.y + bias[f + 1], 0.f);
    *(float2*)(outp + (long long)node * F + f) = acc;
  }
}

extern "C" void kernel_launch(void* const* d_in, const int* in_sizes, int n_in,
                              void* d_out, int out_size, void* d_ws,
                              size_t ws_size, hipStream_t stream) {
  const float* x      = (const float*)d_in[0];
  const void*  ei     = d_in[1];
  const float* W1     = (const float*)d_in[2];
  const float* a1_src = (const float*)d_in[3];
  const float* a1_dst = (const float*)d_in[4];
  const float* b1     = (const float*)d_in[5];
  const float* W2     = (const float*)d_in[6];
  const float* a2_src = (const float*)d_in[7];
  const float* a2_dst = (const float*)d_in[8];
  const float* b2     = (const float*)d_in[9];
  float* out = (float*)d_out;

  const int N = 50000, E = 800000, IN = 128, HID = 256, OUT = 128;
  const int NB_SCAN = (N + 1023) / 1024;

  // ---- workspace carve ----
  char* ws = (char*)d_ws;
  size_t off = 0;
  auto carve = [&](size_t bytes) -> void* {
    void* p = ws + off;
    off = (off + bytes + 255) & ~(size_t)255;
    return p;
  };
  float* h        = (float*)carve((size_t)N * HID * 4);
  float* out1     = (float*)carve((size_t)N * HID * 4);
  int*   csr_src  = (int*)carve((size_t)E * 4);
  int*   deg      = (int*)carve((size_t)N * 4);
  int*   rowstart = (int*)carve((size_t)(N + 1) * 4);
  int*   cursor   = (int*)carve((size_t)N * 4);
  int*   bsum     = (int*)carve((size_t)NB_SCAN * 4);
  float* as_      = (float*)carve((size_t)N * 4);
  float* ad_      = (float*)carve((size_t)N * 4);
  int*   flag64   = (int*)carve(256);
  (void)ws_size; (void)in_sizes; (void)n_in; (void)out_size;

  hipMemsetAsync(deg, 0, (size_t)N * 4, stream);
  detect_idx64_kernel<<<1, 64, 0, stream>>>(ei, flag64);

  // ---- CSR build (once; shared by both layers) ----
  const int ebT = (E + 255) / 256;
  hist_kernel<<<ebT, 256, 0, stream>>>(ei, flag64, E, deg);
  scan1<<<NB_SCAN, 256, 0, stream>>>(deg, rowstart, bsum, N);
  scan2<<<1, 64, 0, stream>>>(bsum, NB_SCAN);
  scan3<<<(N + 256) / 256, 256, 0, stream>>>(rowstart, bsum, cursor, N, E);
  csr_place<<<ebT, 256, 0, stream>>>(ei, flag64, E, cursor, csr_src);

  const int ab = (N * 64 + 255) / 256;   // wave-per-node
  const int nb4 = (N + 3) / 4;           // 4 waves/block node kernels

  // ---- layer 1: x[N,128] -> out1[N,256] ----
  {
    dim3 g((N + 63) / 64, HID / 64);
    gemm_f32<<<g, 256, 0, stream>>>(x, W1, h, N, HID, IN);
  }
  alpha_kernel<<<ab, 256, 0, stream>>>(h, a1_src, a1_dst, as_, ad_, N, HID);
  gat_aggregate<256><<<nb4, 256, 0, stream>>>(rowstart, csr_src, as_, ad_, h,
                                              b1, out1, N);

  // ---- layer 2: out1[N,256] -> out[N,128] ----
  {
    dim3 g((N + 63) / 64, OUT / 64);
    gemm_f32<<<g, 256, 0, stream>>>(out1, W2, h, N, OUT, HID);
  }
  alpha_kernel<<<ab, 256, 0, stream>>>(h, a2_src, a2_dst, as_, ad_, N, OUT);
  gat_aggregate<128><<<nb4, 256, 0, stream>>>(rowstart, csr_src, as_, ad_, h,
                                              b2, out, N);
}

// Round 3
// 298.189 us; speedup vs baseline: 12.9209x; 1.5736x over previous
//
#include <hip/hip_runtime.h>
#include <hip/hip_bf16.h>
#include <float.h>
#include <stdint.h>

#define NEG_SLOPE 0.2f

typedef __attribute__((ext_vector_type(8))) short short8;
typedef __attribute__((ext_vector_type(4))) float f32x4;

__device__ inline float b2f(unsigned short u) {
  return __uint_as_float((unsigned int)u << 16);
}
__device__ inline unsigned short f2b(float f) {
  unsigned int u = __float_as_uint(f);
  return (unsigned short)((u + 0x7FFF + ((u >> 16) & 1)) >> 16);
}
__device__ inline float leaky(float e) { return e >= 0.f ? e : NEG_SLOPE * e; }

// ---------------------------------------------------------------------------
// int32/int64 edge_index detection (device-side, no host sync)
// ---------------------------------------------------------------------------
__global__ void detect_idx64_kernel(const void* ei, int* flag) {
  if (threadIdx.x == 0 && blockIdx.x == 0) {
    const int* p = (const int*)ei;
    int allz = 1;
    for (int j = 1; j < 128; j += 2) {
      if (p[j] != 0) { allz = 0; break; }
    }
    *flag = allz;
  }
}

__device__ inline int load_idx(const void* ei, long long pos, int is64) {
  if (is64) return (int)((const long long*)ei)[pos];
  return ((const int*)ei)[pos];
}

// ---------------------------------------------------------------------------
// CSR build: histogram -> block scan -> global scan -> placement
// ---------------------------------------------------------------------------
__global__ __launch_bounds__(256) void hist_kernel(
    const void* __restrict__ ei, const int* __restrict__ flag64, int E,
    int* __restrict__ deg) {
  const int is64 = *flag64;
  int j = blockIdx.x * blockDim.x + threadIdx.x;
  if (j >= E) return;
  int d = load_idx(ei, (long long)E + j, is64);
  atomicAdd(&deg[d], 1);
}

__global__ __launch_bounds__(256) void scan1(
    const int* __restrict__ deg, int* __restrict__ rowstart,
    int* __restrict__ bsum, int n) {
  __shared__ int tsum[256];
  const int base = blockIdx.x * 1024;
  const int t = threadIdx.x;
  int vals[4];
  int s = 0;
#pragma unroll
  for (int i = 0; i < 4; ++i) {
    int idx = base + t * 4 + i;
    vals[i] = (idx < n) ? deg[idx] : 0;
    s += vals[i];
  }
  tsum[t] = s;
  __syncthreads();
  for (int off = 1; off < 256; off <<= 1) {
    int v = (t >= off) ? tsum[t - off] : 0;
    __syncthreads();
    tsum[t] += v;
    __syncthreads();
  }
  int excl = (t > 0) ? tsum[t - 1] : 0;
#pragma unroll
  for (int i = 0; i < 4; ++i) {
    int idx = base + t * 4 + i;
    if (idx < n) rowstart[idx] = excl;
    excl += vals[i];
  }
  if (t == 255) bsum[blockIdx.x] = tsum[255];
}

__global__ void scan2(int* bsum, int nb) {
  if (threadIdx.x == 0 && blockIdx.x == 0) {
    int run = 0;
    for (int i = 0; i < nb; ++i) {
      int v = bsum[i];
      bsum[i] = run;
      run += v;
    }
  }
}

__global__ __launch_bounds__(256) void scan3(
    int* __restrict__ rowstart, const int* __restrict__ bsum,
    int* __restrict__ cursor, int n, int Etot) {
  int i = blockIdx.x * blockDim.x + threadIdx.x;
  if (i < n) {
    int v = rowstart[i] + bsum[i >> 10];
    rowstart[i] = v;
    cursor[i] = v;
  } else if (i == n) {
    rowstart[n] = Etot;
  }
}

__global__ __launch_bounds__(256) void csr_place(
    const void* __restrict__ ei, const int* __restrict__ flag64, int E,
    int* __restrict__ cursor, int* __restrict__ csr_src) {
  const int is64 = *flag64;
  int j = blockIdx.x * blockDim.x + threadIdx.x;
  if (j >= E) return;
  int s = load_idx(ei, j, is64);
  int d = load_idx(ei, (long long)E + j, is64);
  int pos = atomicAdd(&cursor[d], 1);
  csr_src[pos] = s;
}

// ---------------------------------------------------------------------------
// fp32 -> bf16 cast (vectorized)
// ---------------------------------------------------------------------------
__global__ __launch_bounds__(256) void cast_bf16(
    const float* __restrict__ in, unsigned short* __restrict__ outp,
    long long n4) {
  long long i = (long long)blockIdx.x * blockDim.x + threadIdx.x;
  if (i >= n4) return;
  float4 v = ((const float4*)in)[i];
  ushort4 o;
  o.x = f2b(v.x); o.y = f2b(v.y); o.z = f2b(v.z); o.w = f2b(v.w);
  ((ushort4*)outp)[i] = o;
}

// Pack W [K,N] fp32 -> fragment-ready bf16: Wp[((k>>3)*N + n)*8 + (k&7)]
__global__ __launch_bounds__(256) void pack_w(
    const float* __restrict__ W, unsigned short* __restrict__ Wp, int Kk,
    int Nn) {
  int i = blockIdx.x * blockDim.x + threadIdx.x;
  if (i >= Kk * Nn) return;
  int k = i / Nn, n = i - k * Nn;
  Wp[(((long long)(k >> 3) * Nn + n) << 3) + (k & 7)] = f2b(W[i]);
}

// ---------------------------------------------------------------------------
// MFMA bf16 GEMM, fragments direct from global (no LDS).
// C[M,Nn] = A[M,Kk] * W[Kk,Nn]; A bf16 row-major, W packed, C bf16.
// Block: 4 waves; wave w computes rows [bm+16w, bm+16w+16) x cols [bn,bn+64).
// mfma_f32_16x16x32_bf16 layout: A/B: m|n = lane&15, k=(lane>>4)*8+i;
// D: col = lane&15, row = (lane>>4)*4 + r.
// ---------------------------------------------------------------------------
template <int Nn, int Kk>
__global__ __launch_bounds__(256) void gemm_mfma(
    const unsigned short* __restrict__ A, const unsigned short* __restrict__ Bp,
    unsigned short* __restrict__ C, int M) {
  const int l = threadIdx.x & 63;
  const int wm = threadIdx.x >> 6;
  const int bm = blockIdx.x * 64;
  const int bn = blockIdx.y * 64;
  const int arow = bm + wm * 16 + (l & 15);
  const int kg = l >> 4;

  f32x4 acc[4];
#pragma unroll
  for (int nt = 0; nt < 4; ++nt) acc[nt] = (f32x4){0.f, 0.f, 0.f, 0.f};

  const bool arow_ok = (arow < M);
#pragma unroll
  for (int kk = 0; kk < Kk; kk += 32) {
    short8 afrag;
    if (arow_ok)
      afrag = *(const short8*)(A + (long long)arow * Kk + kk + kg * 8);
    else
      afrag = (short8){0, 0, 0, 0, 0, 0, 0, 0};
    const int kb = (kk >> 3) + kg;
#pragma unroll
    for (int nt = 0; nt < 4; ++nt) {
      short8 bfrag = *(const short8*)(Bp + (((long long)kb * Nn + bn + nt * 16 +
                                             (l & 15))
                                            << 3));
      acc[nt] = __builtin_amdgcn_mfma_f32_16x16x32_bf16(afrag, bfrag, acc[nt],
                                                        0, 0, 0);
    }
  }
#pragma unroll
  for (int nt = 0; nt < 4; ++nt) {
    const int col = bn + nt * 16 + (l & 15);
#pragma unroll
    for (int r = 0; r < 4; ++r) {
      const int row = bm + wm * 16 + (l >> 4) * 4 + r;
      if (row < M) C[(long long)row * Nn + col] = f2b(acc[nt][r]);
    }
  }
}

// ---------------------------------------------------------------------------
// Per-node scores from bf16 h: as[i] = h[i,:]·a_src, ad[i] = h[i,:]·a_dst
// ---------------------------------------------------------------------------
template <int F>
__global__ __launch_bounds__(256) void alpha_kernel(
    const unsigned short* __restrict__ h, const float* __restrict__ a_src,
    const float* __restrict__ a_dst, float* __restrict__ as_out,
    float* __restrict__ ad_out, int Nn) {
  int node = blockIdx.x * (blockDim.x >> 6) + (threadIdx.x >> 6);
  int lane = threadIdx.x & 63;
  if (node >= Nn) return;
  constexpr int VPT = F / 64;
  const unsigned short* row = h + (long long)node * F + lane * VPT;
  float s1 = 0.f, s2 = 0.f;
#pragma unroll
  for (int i = 0; i < VPT; ++i) {
    float v = b2f(row[i]);
    s1 += v * a_src[lane * VPT + i];
    s2 += v * a_dst[lane * VPT + i];
  }
#pragma unroll
  for (int off = 32; off > 0; off >>= 1) {
    s1 += __shfl_down(s1, off);
    s2 += __shfl_down(s2, off);
  }
  if (lane == 0) {
    as_out[node] = s1;
    ad_out[node] = s2;
  }
}

// ---------------------------------------------------------------------------
// Fused softmax + gather-aggregate + bias + ReLU. One wave per node.
// h is bf16. G = 512/F groups process G edges concurrently (16B/lane loads).
// OUT_BF16: write bf16 (layer 1 feeding GEMM2) vs fp32 (final output).
// ---------------------------------------------------------------------------
template <int F, bool OUT_BF16>
__global__ __launch_bounds__(256) void gat_aggregate(
    const int* __restrict__ rowstart, const int* __restrict__ csr_src,
    const float* __restrict__ as, const float* __restrict__ ad,
    const unsigned short* __restrict__ h, const float* __restrict__ bias,
    void* __restrict__ outp, int Nn) {
  constexpr int G = 512 / F;       // edge groups per wave (2 or 4)
  constexpr int LPG = 64 / G;      // lanes per group (32 or 16)
  int node = blockIdx.x * (blockDim.x >> 6) + (threadIdx.x >> 6);
  int lane = threadIdx.x & 63;
  if (node >= Nn) return;
  const int beg = rowstart[node];
  const int end = rowstart[node + 1];
  const float adn = ad[node];
  const float e_self = leaky(as[node] + adn);

  // wave-parallel max (+self)
  float m = e_self;
  for (int t = beg + lane; t < end; t += 64)
    m = fmaxf(m, leaky(as[csr_src[t]] + adn));
#pragma unroll
  for (int off = 32; off > 0; off >>= 1) m = fmaxf(m, __shfl_xor(m, off));

  // wave-parallel denom
  float dsum = 0.f;
  for (int t = beg + lane; t < end; t += 64)
    dsum += __expf(leaky(as[csr_src[t]] + adn) - m);
#pragma unroll
  for (int off = 32; off > 0; off >>= 1) dsum += __shfl_xor(dsum, off);
  const float inv = 1.f / (dsum + __expf(e_self - m) + 1e-16f);

  // group-parallel gather-accumulate: group g handles edges beg+g, +G, ...
  const int grp = lane / LPG;
  const int hl = lane % LPG;
  const int f0 = hl * 8;
  float acc[8] = {};
  if (grp == 0) {  // self-loop
    float a0 = __expf(e_self - m) * inv;
    short8 v = *(const short8*)(h + (long long)node * F + f0);
#pragma unroll
    for (int j = 0; j < 8; ++j) acc[j] += a0 * b2f((unsigned short)v[j]);
  }
  for (int t = beg + grp; t < end; t += G) {
    int s = csr_src[t];
    float al = __expf(leaky(as[s] + adn) - m) * inv;
    short8 v = *(const short8*)(h + (long long)s * F + f0);
#pragma unroll
    for (int j = 0; j < 8; ++j) acc[j] += al * b2f((unsigned short)v[j]);
  }
  // combine groups
#pragma unroll
  for (int off = 32; off >= LPG; off >>= 1) {
#pragma unroll
    for (int j = 0; j < 8; ++j) acc[j] += __shfl_xor(acc[j], off);
  }
  // write (lanes of group 0 only)
  if (lane < LPG) {
#pragma unroll
    for (int j = 0; j < 8; ++j) acc[j] = fmaxf(acc[j] + bias[f0 + j], 0.f);
    if (OUT_BF16) {
      short8 o;
#pragma unroll
      for (int j = 0; j < 8; ++j) o[j] = (short)f2b(acc[j]);
      *(short8*)((unsigned short*)outp + (long long)node * F + f0) = o;
    } else {
      float4 o0 = {acc[0], acc[1], acc[2], acc[3]};
      float4 o1 = {acc[4], acc[5], acc[6], acc[7]};
      float* orow = (float*)outp + (long long)node * F + f0;
      *(float4*)(orow) = o0;
      *(float4*)(orow + 4) = o1;
    }
  }
}

extern "C" void kernel_launch(void* const* d_in, const int* in_sizes, int n_in,
                              void* d_out, int out_size, void* d_ws,
                              size_t ws_size, hipStream_t stream) {
  const float* x      = (const float*)d_in[0];
  const void*  ei     = d_in[1];
  const float* W1     = (const float*)d_in[2];
  const float* a1_src = (const float*)d_in[3];
  const float* a1_dst = (const float*)d_in[4];
  const float* b1     = (const float*)d_in[5];
  const float* W2     = (const float*)d_in[6];
  const float* a2_src = (const float*)d_in[7];
  const float* a2_dst = (const float*)d_in[8];
  const float* b2     = (const float*)d_in[9];
  float* out = (float*)d_out;

  const int N = 50000, E = 800000, IN = 128, HID = 256, OUT = 128;
  const int NB_SCAN = (N + 1023) / 1024;

  char* ws = (char*)d_ws;
  size_t off = 0;
  auto carve = [&](size_t bytes) -> void* {
    void* p = ws + off;
    off = (off + bytes + 255) & ~(size_t)255;
    return p;
  };
  unsigned short* h    = (unsigned short*)carve((size_t)N * HID * 2);  // bf16
  unsigned short* out1 = (unsigned short*)carve((size_t)N * HID * 2);  // bf16
  unsigned short* xb   = (unsigned short*)carve((size_t)N * IN * 2);   // bf16
  unsigned short* Wp1  = (unsigned short*)carve((size_t)IN * HID * 2);
  unsigned short* Wp2  = (unsigned short*)carve((size_t)HID * OUT * 2);
  int*   csr_src  = (int*)carve((size_t)E * 4);
  int*   deg      = (int*)carve((size_t)N * 4);
  int*   rowstart = (int*)carve((size_t)(N + 1) * 4);
  int*   cursor   = (int*)carve((size_t)N * 4);
  int*   bsum     = (int*)carve((size_t)NB_SCAN * 4);
  float* as_      = (float*)carve((size_t)N * 4);
  float* ad_      = (float*)carve((size_t)N * 4);
  int*   flag64   = (int*)carve(256);
  (void)ws_size; (void)in_sizes; (void)n_in; (void)out_size;

  hipMemsetAsync(deg, 0, (size_t)N * 4, stream);
  detect_idx64_kernel<<<1, 64, 0, stream>>>(ei, flag64);

  // CSR build (shared by both layers)
  const int ebT = (E + 255) / 256;
  hist_kernel<<<ebT, 256, 0, stream>>>(ei, flag64, E, deg);
  scan1<<<NB_SCAN, 256, 0, stream>>>(deg, rowstart, bsum, N);
  scan2<<<1, 64, 0, stream>>>(bsum, NB_SCAN);
  scan3<<<(N + 256) / 256, 256, 0, stream>>>(rowstart, bsum, cursor, N, E);
  csr_place<<<ebT, 256, 0, stream>>>(ei, flag64, E, cursor, csr_src);

  // casts + weight packing
  cast_bf16<<<(N * IN / 4 + 255) / 256, 256, 0, stream>>>(x, xb,
                                                          (long long)N * IN / 4);
  pack_w<<<(IN * HID + 255) / 256, 256, 0, stream>>>(W1, Wp1, IN, HID);
  pack_w<<<(HID * OUT + 255) / 256, 256, 0, stream>>>(W2, Wp2, HID, OUT);

  const int ab = (N * 64 + 255) / 256;  // wave-per-node
  const int nb4 = (N + 3) / 4;

  // ---- layer 1: x[N,128] -> out1[N,256] (bf16) ----
  {
    dim3 g((N + 63) / 64, HID / 64);
    gemm_mfma<HID, IN><<<g, 256, 0, stream>>>(xb, Wp1, h, N);
  }
  alpha_kernel<HID><<<ab, 256, 0, stream>>>(h, a1_src, a1_dst, as_, ad_, N);
  gat_aggregate<HID, true><<<nb4, 256, 0, stream>>>(rowstart, csr_src, as_,
                                                    ad_, h, b1, out1, N);

  // ---- layer 2: out1[N,256] -> out[N,128] (fp32) ----
  {
    dim3 g((N + 63) / 64, OUT / 64);
    gemm_mfma<OUT, HID><<<g, 256, 0, stream>>>(out1, Wp2, h, N);
  }
  alpha_kernel<OUT><<<ab, 256, 0, stream>>>(h, a2_src, a2_dst, as_, ad_, N);
  gat_aggregate<OUT, false><<<nb4, 256, 0, stream>>>(rowstart, csr_src, as_,
                                                     ad_, h, b2, out, N);
}

// Round 4
// 271.047 us; speedup vs baseline: 14.2147x; 1.1001x over previous
//
#include <hip/hip_runtime.h>
#include <hip/hip_bf16.h>
#include <float.h>
#include <stdint.h>

#define NEG_SLOPE 0.2f

typedef __attribute__((ext_vector_type(8))) short short8;
typedef __attribute__((ext_vector_type(4))) float f32x4;

__device__ inline float b2f(unsigned short u) {
  return __uint_as_float((unsigned int)u << 16);
}
__device__ inline unsigned short f2b(float f) {
  unsigned int u = __float_as_uint(f);
  return (unsigned short)((u + 0x7FFF + ((u >> 16) & 1)) >> 16);
}
__device__ inline float leaky(float e) { return e >= 0.f ? e : NEG_SLOPE * e; }

// ---------------------------------------------------------------------------
// int32/int64 edge_index detection: int64 values < 50000 => odd words zero.
// Wave-parallel: lane j checks word 2j+1.
// ---------------------------------------------------------------------------
__global__ void detect_idx64_kernel(const void* ei, int* flag) {
  const int* p = (const int*)ei;
  int lane = threadIdx.x & 63;
  unsigned long long b = __ballot(p[2 * lane + 1] != 0);
  if (threadIdx.x == 0) *flag = (b == 0ull) ? 1 : 0;
}

__device__ inline int load_idx(const void* ei, long long pos, int is64) {
  if (is64) return (int)((const long long*)ei)[pos];
  return ((const int*)ei)[pos];
}

// ---------------------------------------------------------------------------
// CSR build: histogram -> block scan -> wave scan -> placement
// ---------------------------------------------------------------------------
__global__ __launch_bounds__(256) void hist_kernel(
    const void* __restrict__ ei, const int* __restrict__ flag64, int E,
    int* __restrict__ deg) {
  const int is64 = *flag64;
  int j = blockIdx.x * blockDim.x + threadIdx.x;
  if (j >= E) return;
  int d = load_idx(ei, (long long)E + j, is64);
  atomicAdd(&deg[d], 1);
}

__global__ __launch_bounds__(256) void scan1(
    const int* __restrict__ deg, int* __restrict__ rowstart,
    int* __restrict__ bsum, int n) {
  __shared__ int tsum[256];
  const int base = blockIdx.x * 1024;
  const int t = threadIdx.x;
  int vals[4];
  int s = 0;
#pragma unroll
  for (int i = 0; i < 4; ++i) {
    int idx = base + t * 4 + i;
    vals[i] = (idx < n) ? deg[idx] : 0;
    s += vals[i];
  }
  tsum[t] = s;
  __syncthreads();
  for (int off = 1; off < 256; off <<= 1) {
    int v = (t >= off) ? tsum[t - off] : 0;
    __syncthreads();
    tsum[t] += v;
    __syncthreads();
  }
  int excl = (t > 0) ? tsum[t - 1] : 0;
#pragma unroll
  for (int i = 0; i < 4; ++i) {
    int idx = base + t * 4 + i;
    if (idx < n) rowstart[idx] = excl;
    excl += vals[i];
  }
  if (t == 255) bsum[blockIdx.x] = tsum[255];
}

// single-wave exclusive scan over block sums (nb <= 64)
__global__ void scan2(int* bsum, int nb) {
  int lane = threadIdx.x;
  int v = (lane < nb) ? bsum[lane] : 0;
  int incl = v;
#pragma unroll
  for (int off = 1; off < 64; off <<= 1) {
    int u = __shfl_up(incl, off);
    if (lane >= off) incl += u;
  }
  if (lane < nb) bsum[lane] = incl - v;
}

__global__ __launch_bounds__(256) void scan3(
    int* __restrict__ rowstart, const int* __restrict__ bsum,
    int* __restrict__ cursor, int n, int Etot) {
  int i = blockIdx.x * blockDim.x + threadIdx.x;
  if (i < n) {
    int v = rowstart[i] + bsum[i >> 10];
    rowstart[i] = v;
    cursor[i] = v;
  } else if (i == n) {
    rowstart[n] = Etot;
  }
}

__global__ __launch_bounds__(256) void csr_place(
    const void* __restrict__ ei, const int* __restrict__ flag64, int E,
    int* __restrict__ cursor, int* __restrict__ csr_src) {
  const int is64 = *flag64;
  int j = blockIdx.x * blockDim.x + threadIdx.x;
  if (j >= E) return;
  int s = load_idx(ei, j, is64);
  int d = load_idx(ei, (long long)E + j, is64);
  int pos = atomicAdd(&cursor[d], 1);
  csr_src[pos] = s;
}

// ---------------------------------------------------------------------------
// One-shot weight prep:
//   blocks [0,128)   : pack W1 [128,256] -> Wp1 fragment layout
//   blocks [128,256) : pack W2 [256,128] -> Wp2 fragment layout
//   blocks [256,259) : wa[768] = {W1@a1s (128), W1@a1d (128),
//                                 W2@a2s (256), W2@a2d (256)}
// pack layout: Wp[((k>>3)*Nn + n)*8 + (k&7)]
// ---------------------------------------------------------------------------
__global__ __launch_bounds__(256) void prep_weights(
    const float* __restrict__ W1, const float* __restrict__ W2,
    const float* __restrict__ a1s, const float* __restrict__ a1d,
    const float* __restrict__ a2s, const float* __restrict__ a2d,
    unsigned short* __restrict__ Wp1, unsigned short* __restrict__ Wp2,
    float* __restrict__ wa) {
  int b = blockIdx.x;
  int t = threadIdx.x;
  if (b < 128) {
    int i = b * 256 + t;
    int k = i >> 8, n = i & 255;  // W1: K=128, N=256
    Wp1[(((k >> 3) * 256 + n) << 3) + (k & 7)] = f2b(W1[i]);
  } else if (b < 256) {
    int i = (b - 128) * 256 + t;
    int k = i >> 7, n = i & 127;  // W2: K=256, N=128
    Wp2[(((k >> 3) * 128 + n) << 3) + (k & 7)] = f2b(W2[i]);
  } else {
    int o = (b - 256) * 256 + t;  // o in [0,768)
    float s = 0.f;
    if (o < 128) {
      for (int n = 0; n < 256; ++n) s += W1[o * 256 + n] * a1s[n];
    } else if (o < 256) {
      int k = o - 128;
      for (int n = 0; n < 256; ++n) s += W1[k * 256 + n] * a1d[n];
    } else if (o < 512) {
      int k = o - 256;
      for (int n = 0; n < 128; ++n) s += W2[k * 128 + n] * a2s[n];
    } else {
      int k = o - 512;
      for (int n = 0; n < 128; ++n) s += W2[k * 128 + n] * a2d[n];
    }
    wa[o] = s;
  }
}

// ---------------------------------------------------------------------------
// Layer-1 scores + cast: one wave per node over fp32 x [N,128].
// as = x·wa_s, ad = x·wa_d; also writes bf16 copy of x.
// ---------------------------------------------------------------------------
__global__ __launch_bounds__(256) void alpha1_cast(
    const float* __restrict__ x, const float* __restrict__ wa,
    unsigned short* __restrict__ xb, float* __restrict__ as_out,
    float* __restrict__ ad_out, int Nn) {
  int node = blockIdx.x * 4 + (threadIdx.x >> 6);
  int lane = threadIdx.x & 63;
  if (node >= Nn) return;
  float2 v = *(const float2*)(x + (long long)node * 128 + lane * 2);
  float s1 = v.x * wa[lane * 2] + v.y * wa[lane * 2 + 1];
  float s2 = v.x * wa[128 + lane * 2] + v.y * wa[128 + lane * 2 + 1];
  unsigned int packed =
      (unsigned int)f2b(v.x) | ((unsigned int)f2b(v.y) << 16);
  *(unsigned int*)(xb + (long long)node * 128 + lane * 2) = packed;
#pragma unroll
  for (int off = 32; off > 0; off >>= 1) {
    s1 += __shfl_down(s1, off);
    s2 += __shfl_down(s2, off);
  }
  if (lane == 0) {
    as_out[node] = s1;
    ad_out[node] = s2;
  }
}

// ---------------------------------------------------------------------------
// Layer-2 scores: one wave per node over bf16 out1 [N,256].
// ---------------------------------------------------------------------------
__global__ __launch_bounds__(256) void alpha2(
    const unsigned short* __restrict__ h, const float* __restrict__ was,
    const float* __restrict__ wad, float* __restrict__ as_out,
    float* __restrict__ ad_out, int Nn) {
  int node = blockIdx.x * 4 + (threadIdx.x >> 6);
  int lane = threadIdx.x & 63;
  if (node >= Nn) return;
  ushort4 v = *(const ushort4*)(h + (long long)node * 256 + lane * 4);
  float s1 = 0.f, s2 = 0.f;
  unsigned short e[4] = {v.x, v.y, v.z, v.w};
#pragma unroll
  for (int i = 0; i < 4; ++i) {
    float f = b2f(e[i]);
    s1 += f * was[lane * 4 + i];
    s2 += f * wad[lane * 4 + i];
  }
#pragma unroll
  for (int off = 32; off > 0; off >>= 1) {
    s1 += __shfl_down(s1, off);
    s2 += __shfl_down(s2, off);
  }
  if (lane == 0) {
    as_out[node] = s1;
    ad_out[node] = s2;
  }
}

// ---------------------------------------------------------------------------
// MFMA bf16 GEMM, fragments direct from global. Optional bias+ReLU epilogue.
// C[M,Nn] = A[M,Kk] * W[Kk,Nn]; A bf16 row-major, W packed, C bf16.
// ---------------------------------------------------------------------------
template <int Nn, int Kk, bool BIAS_RELU>
__global__ __launch_bounds__(256) void gemm_mfma(
    const unsigned short* __restrict__ A, const unsigned short* __restrict__ Bp,
    unsigned short* __restrict__ C, int M, const float* __restrict__ bias) {
  const int l = threadIdx.x & 63;
  const int wm = threadIdx.x >> 6;
  const int bm = blockIdx.x * 64;
  const int bn = blockIdx.y * 64;
  const int arow = bm + wm * 16 + (l & 15);
  const int kg = l >> 4;

  f32x4 acc[4];
#pragma unroll
  for (int nt = 0; nt < 4; ++nt) acc[nt] = (f32x4){0.f, 0.f, 0.f, 0.f};

  const bool arow_ok = (arow < M);
#pragma unroll
  for (int kk = 0; kk < Kk; kk += 32) {
    short8 afrag;
    if (arow_ok)
      afrag = *(const short8*)(A + (long long)arow * Kk + kk + kg * 8);
    else
      afrag = (short8){0, 0, 0, 0, 0, 0, 0, 0};
    const int kb = (kk >> 3) + kg;
#pragma unroll
    for (int nt = 0; nt < 4; ++nt) {
      short8 bfrag = *(const short8*)(Bp + (((long long)kb * Nn + bn + nt * 16 +
                                             (l & 15))
                                            << 3));
      acc[nt] = __builtin_amdgcn_mfma_f32_16x16x32_bf16(afrag, bfrag, acc[nt],
                                                        0, 0, 0);
    }
  }
#pragma unroll
  for (int nt = 0; nt < 4; ++nt) {
    const int col = bn + nt * 16 + (l & 15);
    float bv = BIAS_RELU ? bias[col] : 0.f;
#pragma unroll
    for (int r = 0; r < 4; ++r) {
      const int row = bm + wm * 16 + (l >> 4) * 4 + r;
      if (row < M) {
        float v = acc[nt][r];
        if (BIAS_RELU) v = fmaxf(v + bv, 0.f);
        C[(long long)row * Nn + col] = f2b(v);
      }
    }
  }
}

// ---------------------------------------------------------------------------
// Fused softmax + gather-aggregate (+ optional bias+ReLU). One wave per node.
// F=128: 4 edge groups x 16 lanes, 8 bf16 (16B) per lane.
// ---------------------------------------------------------------------------
template <bool BIAS_RELU, bool OUT_BF16>
__global__ __launch_bounds__(256) void gat_aggregate(
    const int* __restrict__ rowstart, const int* __restrict__ csr_src,
    const float* __restrict__ as, const float* __restrict__ ad,
    const unsigned short* __restrict__ h, const float* __restrict__ bias,
    void* __restrict__ outp, int Nn) {
  constexpr int F = 128;
  constexpr int G = 4;    // edge groups per wave
  constexpr int LPG = 16; // lanes per group
  int node = blockIdx.x * 4 + (threadIdx.x >> 6);
  int lane = threadIdx.x & 63;
  if (node >= Nn) return;
  const int beg = rowstart[node];
  const int end = rowstart[node + 1];
  const float adn = ad[node];
  const float e_self = leaky(as[node] + adn);

  // wave-parallel max (+self)
  float m = e_self;
  for (int t = beg + lane; t < end; t += 64)
    m = fmaxf(m, leaky(as[csr_src[t]] + adn));
#pragma unroll
  for (int off = 32; off > 0; off >>= 1) m = fmaxf(m, __shfl_xor(m, off));

  // wave-parallel denom
  float dsum = 0.f;
  for (int t = beg + lane; t < end; t += 64)
    dsum += __expf(leaky(as[csr_src[t]] + adn) - m);
#pragma unroll
  for (int off = 32; off > 0; off >>= 1) dsum += __shfl_xor(dsum, off);
  const float inv = 1.f / (dsum + __expf(e_self - m) + 1e-16f);

  // group-parallel gather-accumulate
  const int grp = lane >> 4;
  const int hl = lane & 15;
  const int f0 = hl * 8;
  float acc[8] = {};
  if (grp == 0) {  // self-loop
    float a0 = __expf(e_self - m) * inv;
    short8 v = *(const short8*)(h + (long long)node * F + f0);
#pragma unroll
    for (int j = 0; j < 8; ++j) acc[j] += a0 * b2f((unsigned short)v[j]);
  }
  for (int t = beg + grp; t < end; t += G) {
    int s = csr_src[t];
    float al = __expf(leaky(as[s] + adn) - m) * inv;
    short8 v = *(const short8*)(h + (long long)s * F + f0);
#pragma unroll
    for (int j = 0; j < 8; ++j) acc[j] += al * b2f((unsigned short)v[j]);
  }
  // combine the 4 groups
#pragma unroll
  for (int off = 32; off >= LPG; off >>= 1) {
#pragma unroll
    for (int j = 0; j < 8; ++j) acc[j] += __shfl_xor(acc[j], off);
  }
  if (lane < LPG) {
    if (BIAS_RELU) {
#pragma unroll
      for (int j = 0; j < 8; ++j) acc[j] = fmaxf(acc[j] + bias[f0 + j], 0.f);
    }
    if (OUT_BF16) {
      short8 o;
#pragma unroll
      for (int j = 0; j < 8; ++j) o[j] = (short)f2b(acc[j]);
      *(short8*)((unsigned short*)outp + (long long)node * F + f0) = o;
    } else {
      float4 o0 = {acc[0], acc[1], acc[2], acc[3]};
      float4 o1 = {acc[4], acc[5], acc[6], acc[7]};
      float* orow = (float*)outp + (long long)node * F + f0;
      *(float4*)(orow) = o0;
      *(float4*)(orow + 4) = o1;
    }
  }
}

extern "C" void kernel_launch(void* const* d_in, const int* in_sizes, int n_in,
                              void* d_out, int out_size, void* d_ws,
                              size_t ws_size, hipStream_t stream) {
  const float* x      = (const float*)d_in[0];
  const void*  ei     = d_in[1];
  const float* W1     = (const float*)d_in[2];
  const float* a1_src = (const float*)d_in[3];
  const float* a1_dst = (const float*)d_in[4];
  const float* b1     = (const float*)d_in[5];
  const float* W2     = (const float*)d_in[6];
  const float* a2_src = (const float*)d_in[7];
  const float* a2_dst = (const float*)d_in[8];
  const float* b2     = (const float*)d_in[9];
  float* out = (float*)d_out;

  const int N = 50000, E = 800000, IN = 128, HID = 256, OUT = 128;
  const int NB_SCAN = (N + 1023) / 1024;

  char* ws = (char*)d_ws;
  size_t off = 0;
  auto carve = [&](size_t bytes) -> void* {
    void* p = ws + off;
    off = (off + bytes + 255) & ~(size_t)255;
    return p;
  };
  unsigned short* xb   = (unsigned short*)carve((size_t)N * IN * 2);   // bf16 x
  unsigned short* aggx = (unsigned short*)carve((size_t)N * IN * 2);   // agg x
  unsigned short* out1 = (unsigned short*)carve((size_t)N * HID * 2);  // layer1
  unsigned short* h2   = (unsigned short*)carve((size_t)N * OUT * 2);  // xW2
  unsigned short* Wp1  = (unsigned short*)carve((size_t)IN * HID * 2);
  unsigned short* Wp2  = (unsigned short*)carve((size_t)HID * OUT * 2);
  float* wa       = (float*)carve(768 * 4);
  int*   csr_src  = (int*)carve((size_t)E * 4);
  int*   deg      = (int*)carve((size_t)N * 4);
  int*   rowstart = (int*)carve((size_t)(N + 1) * 4);
  int*   cursor   = (int*)carve((size_t)N * 4);
  int*   bsum     = (int*)carve((size_t)NB_SCAN * 4);
  float* as_      = (float*)carve((size_t)N * 4);
  float* ad_      = (float*)carve((size_t)N * 4);
  int*   flag64   = (int*)carve(256);
  (void)ws_size; (void)in_sizes; (void)n_in; (void)out_size;

  hipMemsetAsync(deg, 0, (size_t)N * 4, stream);
  detect_idx64_kernel<<<1, 64, 0, stream>>>(ei, flag64);

  // CSR build (shared by both layers)
  const int ebT = (E + 255) / 256;
  hist_kernel<<<ebT, 256, 0, stream>>>(ei, flag64, E, deg);
  scan1<<<NB_SCAN, 256, 0, stream>>>(deg, rowstart, bsum, N);
  scan2<<<1, 64, 0, stream>>>(bsum, NB_SCAN);
  scan3<<<(N + 256) / 256, 256, 0, stream>>>(rowstart, bsum, cursor, N, E);
  csr_place<<<ebT, 256, 0, stream>>>(ei, flag64, E, cursor, csr_src);

  // weights: pack W1/W2 + 4 matvecs, one dispatch
  prep_weights<<<259, 256, 0, stream>>>(W1, W2, a1_src, a1_dst, a2_src, a2_dst,
                                        Wp1, Wp2, wa);

  const int nb4 = (N + 3) / 4;  // wave-per-node kernels

  // ---- layer 1: scores from x, aggregate x, then GEMM(+bias+ReLU) ----
  alpha1_cast<<<nb4, 256, 0, stream>>>(x, wa, xb, as_, ad_, N);
  gat_aggregate<false, true><<<nb4, 256, 0, stream>>>(rowstart, csr_src, as_,
                                                      ad_, xb, nullptr, aggx, N);
  {
    dim3 g((N + 63) / 64, HID / 64);
    gemm_mfma<HID, IN, true><<<g, 256, 0, stream>>>(aggx, Wp1, out1, N, b1);
  }

  // ---- layer 2: scores from out1, GEMM, aggregate h2 (+bias+ReLU) ----
  alpha2<<<nb4, 256, 0, stream>>>(out1, wa + 256, wa + 512, as_, ad_, N);
  {
    dim3 g((N + 63) / 64, OUT / 64);
    gemm_mfma<OUT, HID, false><<<g, 256, 0, stream>>>(out1, Wp2, h2, N, nullptr);
  }
  gat_aggregate<true, false><<<nb4, 256, 0, stream>>>(rowstart, csr_src, as_,
                                                      ad_, h2, b2, out, N);
}

// Round 5
// 206.499 us; speedup vs baseline: 18.6580x; 1.3126x over previous
//
#include <hip/hip_runtime.h>
#include <hip/hip_bf16.h>
#include <float.h>
#include <stdint.h>

#define NEG_SLOPE 0.2f

typedef __attribute__((ext_vector_type(8))) short short8;
typedef __attribute__((ext_vector_type(4))) float f32x4;

__device__ inline float b2f(unsigned short u) {
  return __uint_as_float((unsigned int)u << 16);
}
__device__ inline unsigned short f2b(float f) {
  unsigned int u = __float_as_uint(f);
  return (unsigned short)((u + 0x7FFF + ((u >> 16) & 1)) >> 16);
}
__device__ inline float leaky(float e) { return e >= 0.f ? e : NEG_SLOPE * e; }

// ---------------------------------------------------------------------------
// int32/int64 edge_index detection: int64 values < 50000 => odd words zero.
// ---------------------------------------------------------------------------
__global__ void detect_idx64_kernel(const void* ei, int* flag) {
  const int* p = (const int*)ei;
  int lane = threadIdx.x & 63;
  unsigned long long b = __ballot(p[2 * lane + 1] != 0);
  if (threadIdx.x == 0) *flag = (b == 0ull) ? 1 : 0;
}

__device__ inline int load_idx(const void* ei, long long pos, int is64) {
  if (is64) return (int)((const long long*)ei)[pos];
  return ((const int*)ei)[pos];
}

// ===========================================================================
// CSR build, XCD-ownership version.
// Buckets of 128 dst nodes (bucket = dst>>7). NB = ceil(N/128) buckets.
// A0: per-bucket histogram (LDS-staged).
// scanB: exclusive scan of bucket counts -> bucket_base, bcursor.
// binA: block-radix scatter of edges into bucket-grouped `binned` array,
//       entries packed (bucket<<23)|(src<<7)|(dst&127).
// placeB: one block per bucket: per-node deg + LDS scan -> rowstart,
//         then LDS-cursor scatter csr[pos]=src (ushort). All writes to a
//         bucket's csr region come from ONE block => no L2 line bouncing.
// ===========================================================================
__global__ __launch_bounds__(256) void bucket_hist_kernel(
    const void* __restrict__ ei, const int* __restrict__ flag64, int E,
    unsigned int* __restrict__ bhist) {
  __shared__ int lh[512];
  int t = threadIdx.x;
  lh[t] = 0; lh[t + 256] = 0;
  __syncthreads();
  const int is64 = *flag64;
  const long long base = (long long)blockIdx.x * 2048;
#pragma unroll
  for (int i = 0; i < 8; ++i) {
    long long j = base + t + i * 256;
    if (j < E) {
      int d = load_idx(ei, (long long)E + j, is64);
      atomicAdd(&lh[d >> 7], 1);
    }
  }
  __syncthreads();
  if (lh[t]) atomicAdd(&bhist[t], (unsigned)lh[t]);
  if (lh[t + 256]) atomicAdd(&bhist[t + 256], (unsigned)lh[t + 256]);
}

__global__ void scan_buckets(const unsigned int* __restrict__ bhist,
                             int* __restrict__ bucket_base,
                             int* __restrict__ bcursor) {
  __shared__ int h[512];
  int t = threadIdx.x;
  h[t] = (int)bhist[t];
  h[t + 256] = (int)bhist[t + 256];
  __syncthreads();
  for (int off = 1; off < 512; off <<= 1) {
    int v0 = (t >= off) ? h[t - off] : 0;
    int v1 = h[t + 256 - off];
    __syncthreads();
    h[t] += v0;
    h[t + 256] += v1;
    __syncthreads();
  }
  int e0 = (t == 0) ? 0 : h[t - 1];
  int e1 = h[t + 255];
  bucket_base[t] = e0; bcursor[t] = e0;
  bucket_base[t + 256] = e1; bcursor[t + 256] = e1;
}

__global__ __launch_bounds__(256) void bin_edges(
    const void* __restrict__ ei, const int* __restrict__ flag64, int E,
    int* __restrict__ bcursor, unsigned int* __restrict__ binned) {
  __shared__ int hist[512];
  __shared__ int scn[512];
  __shared__ int gb[512];
  __shared__ unsigned int stage[2048];
  int t = threadIdx.x;
  hist[t] = 0; hist[t + 256] = 0;
  __syncthreads();
  const int is64 = *flag64;
  const long long base = (long long)blockIdx.x * 2048;
  const int cblk = (int)min((long long)2048, (long long)E - base);
  int sv[8];
  short bk[8], rk[8];
#pragma unroll
  for (int i = 0; i < 8; ++i) {
    int k = t + i * 256;
    if (k < cblk) {
      long long j = base + k;
      int s = load_idx(ei, j, is64);
      int d = load_idx(ei, (long long)E + j, is64);
      int b = d >> 7;
      bk[i] = (short)b;
      sv[i] = (s << 7) | (d & 127);
      rk[i] = (short)atomicAdd(&hist[b], 1);
    } else {
      bk[i] = -1;
    }
  }
  __syncthreads();
  scn[t] = hist[t]; scn[t + 256] = hist[t + 256];
  __syncthreads();
  for (int off = 1; off < 512; off <<= 1) {
    int v0 = (t >= off) ? scn[t - off] : 0;
    int v1 = scn[t + 256 - off];
    __syncthreads();
    scn[t] += v0;
    scn[t + 256] += v1;
    __syncthreads();
  }
  int c0 = hist[t], c1 = hist[t + 256];
  int l0 = scn[t] - c0, l1 = scn[t + 256] - c1;
  if (c0) gb[t] = atomicAdd(&bcursor[t], c0);
  if (c1) gb[t + 256] = atomicAdd(&bcursor[t + 256], c1);
  scn[t] = l0; scn[t + 256] = l1;
  __syncthreads();
#pragma unroll
  for (int i = 0; i < 8; ++i) {
    if (bk[i] >= 0)
      stage[scn[bk[i]] + rk[i]] = ((unsigned)(int)bk[i] << 23) | (unsigned)sv[i];
  }
  __syncthreads();
#pragma unroll
  for (int i = 0; i < 8; ++i) {
    int k = t + i * 256;
    if (k < cblk) {
      unsigned w = stage[k];
      int b = w >> 23;
      binned[gb[b] + (k - scn[b])] = w;
    }
  }
}

__global__ __launch_bounds__(256) void place_csr(
    const unsigned int* __restrict__ binned,
    const int* __restrict__ bucket_base, int* __restrict__ rowstart,
    unsigned short* __restrict__ csr, int Nn, int E) {
  __shared__ int cnt[128], deg0[128], cur[128];
  int t = threadIdx.x;
  int b = blockIdx.x;
  if (t < 128) cnt[t] = 0;
  __syncthreads();
  const int rbeg = bucket_base[b], rend = bucket_base[b + 1];
  for (int k = rbeg + t; k < rend; k += 256)
    atomicAdd(&cnt[binned[k] & 127], 1);
  __syncthreads();
  if (t < 128) deg0[t] = cnt[t];
  __syncthreads();
  for (int off = 1; off < 128; off <<= 1) {
    int v = (t >= off && t < 128) ? cnt[t - off] : 0;
    __syncthreads();
    if (t < 128) cnt[t] += v;
    __syncthreads();
  }
  const int node0 = b << 7;
  if (t < 128) {
    int start = rbeg + cnt[t] - deg0[t];
    int node = node0 + t;
    if (node < Nn) rowstart[node] = start;
    cur[t] = start;
  }
  if (b == 0 && t == 0) rowstart[Nn] = E;
  __syncthreads();
  for (int k = rbeg + t; k < rend; k += 256) {
    unsigned w = binned[k];
    int pos = atomicAdd(&cur[w & 127], 1);
    csr[pos] = (unsigned short)((w >> 7) & 0xFFFF);
  }
}

// ---------------------------------------------------------------------------
// One-shot weight prep: pack W1/W2 to fragment layout + 4 matvecs
// wa[768] = {W1@a1s, W1@a1d, W2@a2s, W2@a2d}
// ---------------------------------------------------------------------------
__global__ __launch_bounds__(256) void prep_weights(
    const float* __restrict__ W1, const float* __restrict__ W2,
    const float* __restrict__ a1s, const float* __restrict__ a1d,
    const float* __restrict__ a2s, const float* __restrict__ a2d,
    unsigned short* __restrict__ Wp1, unsigned short* __restrict__ Wp2,
    float* __restrict__ wa) {
  int b = blockIdx.x;
  int t = threadIdx.x;
  if (b < 128) {
    int i = b * 256 + t;
    int k = i >> 8, n = i & 255;
    Wp1[(((k >> 3) * 256 + n) << 3) + (k & 7)] = f2b(W1[i]);
  } else if (b < 256) {
    int i = (b - 128) * 256 + t;
    int k = i >> 7, n = i & 127;
    Wp2[(((k >> 3) * 128 + n) << 3) + (k & 7)] = f2b(W2[i]);
  } else {
    int o = (b - 256) * 256 + t;
    float s = 0.f;
    if (o < 128) {
      for (int n = 0; n < 256; ++n) s += W1[o * 256 + n] * a1s[n];
    } else if (o < 256) {
      int k = o - 128;
      for (int n = 0; n < 256; ++n) s += W1[k * 256 + n] * a1d[n];
    } else if (o < 512) {
      int k = o - 256;
      for (int n = 0; n < 128; ++n) s += W2[k * 128 + n] * a2s[n];
    } else {
      int k = o - 512;
      for (int n = 0; n < 128; ++n) s += W2[k * 128 + n] * a2d[n];
    }
    wa[o] = s;
  }
}

// ---------------------------------------------------------------------------
// Layer-1 scores + bf16 cast of x (one wave per node, fp32 x [N,128])
// ---------------------------------------------------------------------------
__global__ __launch_bounds__(256) void alpha1_cast(
    const float* __restrict__ x, const float* __restrict__ wa,
    unsigned short* __restrict__ xb, float* __restrict__ as_out,
    float* __restrict__ ad_out, int Nn) {
  int node = blockIdx.x * 4 + (threadIdx.x >> 6);
  int lane = threadIdx.x & 63;
  if (node >= Nn) return;
  float2 v = *(const float2*)(x + (long long)node * 128 + lane * 2);
  float s1 = v.x * wa[lane * 2] + v.y * wa[lane * 2 + 1];
  float s2 = v.x * wa[128 + lane * 2] + v.y * wa[128 + lane * 2 + 1];
  unsigned int packed = (unsigned int)f2b(v.x) | ((unsigned int)f2b(v.y) << 16);
  *(unsigned int*)(xb + (long long)node * 128 + lane * 2) = packed;
#pragma unroll
  for (int off = 32; off > 0; off >>= 1) {
    s1 += __shfl_down(s1, off);
    s2 += __shfl_down(s2, off);
  }
  if (lane == 0) {
    as_out[node] = s1;
    ad_out[node] = s2;
  }
}

// ---------------------------------------------------------------------------
// Layer-2 scores from bf16 out1 [N,256]
// ---------------------------------------------------------------------------
__global__ __launch_bounds__(256) void alpha2(
    const unsigned short* __restrict__ h, const float* __restrict__ was,
    const float* __restrict__ wad, float* __restrict__ as_out,
    float* __restrict__ ad_out, int Nn) {
  int node = blockIdx.x * 4 + (threadIdx.x >> 6);
  int lane = threadIdx.x & 63;
  if (node >= Nn) return;
  ushort4 v = *(const ushort4*)(h + (long long)node * 256 + lane * 4);
  float s1 = 0.f, s2 = 0.f;
  unsigned short e[4] = {v.x, v.y, v.z, v.w};
#pragma unroll
  for (int i = 0; i < 4; ++i) {
    float f = b2f(e[i]);
    s1 += f * was[lane * 4 + i];
    s2 += f * wad[lane * 4 + i];
  }
#pragma unroll
  for (int off = 32; off > 0; off >>= 1) {
    s1 += __shfl_down(s1, off);
    s2 += __shfl_down(s2, off);
  }
  if (lane == 0) {
    as_out[node] = s1;
    ad_out[node] = s2;
  }
}

// ---------------------------------------------------------------------------
// MFMA bf16 GEMM, fragments direct from global. Optional bias+ReLU epilogue.
// ---------------------------------------------------------------------------
template <int Nn, int Kk, bool BIAS_RELU>
__global__ __launch_bounds__(256) void gemm_mfma(
    const unsigned short* __restrict__ A, const unsigned short* __restrict__ Bp,
    unsigned short* __restrict__ C, int M, const float* __restrict__ bias) {
  const int l = threadIdx.x & 63;
  const int wm = threadIdx.x >> 6;
  const int bm = blockIdx.x * 64;
  const int bn = blockIdx.y * 64;
  const int arow = bm + wm * 16 + (l & 15);
  const int kg = l >> 4;

  f32x4 acc[4];
#pragma unroll
  for (int nt = 0; nt < 4; ++nt) acc[nt] = (f32x4){0.f, 0.f, 0.f, 0.f};

  const bool arow_ok = (arow < M);
#pragma unroll
  for (int kk = 0; kk < Kk; kk += 32) {
    short8 afrag;
    if (arow_ok)
      afrag = *(const short8*)(A + (long long)arow * Kk + kk + kg * 8);
    else
      afrag = (short8){0, 0, 0, 0, 0, 0, 0, 0};
    const int kb = (kk >> 3) + kg;
#pragma unroll
    for (int nt = 0; nt < 4; ++nt) {
      short8 bfrag = *(const short8*)(Bp + (((long long)kb * Nn + bn + nt * 16 +
                                             (l & 15))
                                            << 3));
      acc[nt] = __builtin_amdgcn_mfma_f32_16x16x32_bf16(afrag, bfrag, acc[nt],
                                                        0, 0, 0);
    }
  }
#pragma unroll
  for (int nt = 0; nt < 4; ++nt) {
    const int col = bn + nt * 16 + (l & 15);
    float bv = BIAS_RELU ? bias[col] : 0.f;
#pragma unroll
    for (int r = 0; r < 4; ++r) {
      const int row = bm + wm * 16 + (l >> 4) * 4 + r;
      if (row < M) {
        float v = acc[nt][r];
        if (BIAS_RELU) v = fmaxf(v + bv, 0.f);
        C[(long long)row * Nn + col] = f2b(v);
      }
    }
  }
}

// ---------------------------------------------------------------------------
// Fused online-softmax + gather-aggregate (+ optional bias+ReLU).
// One wave per node; single online (m, sum) pass, then gather pass with
// 4 edge groups x 16 lanes (16B bf16 loads per lane).
// ---------------------------------------------------------------------------
template <bool BIAS_RELU, bool OUT_BF16>
__global__ __launch_bounds__(256) void gat_aggregate(
    const int* __restrict__ rowstart, const unsigned short* __restrict__ csr,
    const float* __restrict__ as, const float* __restrict__ ad,
    const unsigned short* __restrict__ h, const float* __restrict__ bias,
    void* __restrict__ outp, int Nn) {
  constexpr int F = 128;
  int node = blockIdx.x * 4 + (threadIdx.x >> 6);
  int lane = threadIdx.x & 63;
  if (node >= Nn) return;
  const int beg = rowstart[node];
  const int end = rowstart[node + 1];
  const float adn = ad[node];
  const float e_self = leaky(as[node] + adn);

  // single online pass: running (m, dsum). Self-loop seeded on lane 0.
  float m = (lane == 0) ? e_self : -3.4e38f;
  float dsum = (lane == 0) ? 1.f : 0.f;
  for (int t = beg + lane; t < end; t += 64) {
    float e = leaky(as[csr[t]] + adn);
    float mn = fmaxf(m, e);
    dsum = dsum * __expf(m - mn) + __expf(e - mn);
    m = mn;
  }
#pragma unroll
  for (int off = 32; off > 0; off >>= 1) {
    float mo = __shfl_xor(m, off);
    float so = __shfl_xor(dsum, off);
    float mn = fmaxf(m, mo);
    dsum = dsum * __expf(m - mn) + so * __expf(mo - mn);
    m = mn;
  }
  const float inv = 1.f / (dsum + 1e-16f);

  // gather pass: group-parallel over edges
  const int grp = lane >> 4;
  const int hl = lane & 15;
  const int f0 = hl * 8;
  float acc[8] = {};
  if (grp == 0) {  // self-loop
    float a0 = __expf(e_self - m) * inv;
    short8 v = *(const short8*)(h + (long long)node * F + f0);
#pragma unroll
    for (int j = 0; j < 8; ++j) acc[j] += a0 * b2f((unsigned short)v[j]);
  }
  for (int t = beg + grp; t < end; t += 4) {
    int s = csr[t];
    float al = __expf(leaky(as[s] + adn) - m) * inv;
    short8 v = *(const short8*)(h + (long long)s * F + f0);
#pragma unroll
    for (int j = 0; j < 8; ++j) acc[j] += al * b2f((unsigned short)v[j]);
  }
#pragma unroll
  for (int off = 32; off >= 16; off >>= 1) {
#pragma unroll
    for (int j = 0; j < 8; ++j) acc[j] += __shfl_xor(acc[j], off);
  }
  if (lane < 16) {
    if (BIAS_RELU) {
#pragma unroll
      for (int j = 0; j < 8; ++j) acc[j] = fmaxf(acc[j] + bias[f0 + j], 0.f);
    }
    if (OUT_BF16) {
      short8 o;
#pragma unroll
      for (int j = 0; j < 8; ++j) o[j] = (short)f2b(acc[j]);
      *(short8*)((unsigned short*)outp + (long long)node * F + f0) = o;
    } else {
      float4 o0 = {acc[0], acc[1], acc[2], acc[3]};
      float4 o1 = {acc[4], acc[5], acc[6], acc[7]};
      float* orow = (float*)outp + (long long)node * F + f0;
      *(float4*)(orow) = o0;
      *(float4*)(orow + 4) = o1;
    }
  }
}

extern "C" void kernel_launch(void* const* d_in, const int* in_sizes, int n_in,
                              void* d_out, int out_size, void* d_ws,
                              size_t ws_size, hipStream_t stream) {
  const float* x      = (const float*)d_in[0];
  const void*  ei     = d_in[1];
  const float* W1     = (const float*)d_in[2];
  const float* a1_src = (const float*)d_in[3];
  const float* a1_dst = (const float*)d_in[4];
  const float* b1     = (const float*)d_in[5];
  const float* W2     = (const float*)d_in[6];
  const float* a2_src = (const float*)d_in[7];
  const float* a2_dst = (const float*)d_in[8];
  const float* b2     = (const float*)d_in[9];
  float* out = (float*)d_out;

  const int N = 50000, E = 800000, IN = 128, HID = 256, OUT = 128;
  const int NB = (N + 127) >> 7;                 // 391 buckets
  const int NBLK_E = (E + 2047) / 2048;          // 391 edge blocks

  char* ws = (char*)d_ws;
  size_t off = 0;
  auto carve = [&](size_t bytes) -> void* {
    void* p = ws + off;
    off = (off + bytes + 255) & ~(size_t)255;
    return p;
  };
  unsigned short* xb     = (unsigned short*)carve((size_t)N * IN * 2);
  unsigned short* aggx   = (unsigned short*)carve((size_t)N * IN * 2);
  unsigned short* out1   = (unsigned short*)carve((size_t)N * HID * 2);
  unsigned short* h2     = (unsigned short*)carve((size_t)N * OUT * 2);
  unsigned short* Wp1    = (unsigned short*)carve((size_t)IN * HID * 2);
  unsigned short* Wp2    = (unsigned short*)carve((size_t)HID * OUT * 2);
  float*          wa     = (float*)carve(768 * 4);
  unsigned int*   binned = (unsigned int*)carve((size_t)E * 4);
  unsigned short* csr    = (unsigned short*)carve((size_t)E * 2);
  unsigned int*   bhist  = (unsigned int*)carve(512 * 4);
  int*            bbase  = (int*)carve(513 * 4);
  int*            bcur   = (int*)carve(512 * 4);
  int*            rowstart = (int*)carve((size_t)(N + 1) * 4);
  float*          as_    = (float*)carve((size_t)N * 4);
  float*          ad_    = (float*)carve((size_t)N * 4);
  int*            flag64 = (int*)carve(256);
  (void)ws_size; (void)in_sizes; (void)n_in; (void)out_size;

  hipMemsetAsync(bhist, 0, 512 * 4, stream);
  detect_idx64_kernel<<<1, 64, 0, stream>>>(ei, flag64);

  // ---- CSR build (bucketed, XCD-exclusive writes) ----
  bucket_hist_kernel<<<NBLK_E, 256, 0, stream>>>(ei, flag64, E, bhist);
  scan_buckets<<<1, 256, 0, stream>>>(bhist, bbase, bcur);
  bin_edges<<<NBLK_E, 256, 0, stream>>>(ei, flag64, E, bcur, binned);
  place_csr<<<NB, 256, 0, stream>>>(binned, bbase, rowstart, csr, N, E);

  // ---- weights ----
  prep_weights<<<259, 256, 0, stream>>>(W1, W2, a1_src, a1_dst, a2_src, a2_dst,
                                        Wp1, Wp2, wa);

  const int nb4 = (N + 3) / 4;

  // ---- layer 1: scores from x, aggregate x, then GEMM(+bias+ReLU) ----
  alpha1_cast<<<nb4, 256, 0, stream>>>(x, wa, xb, as_, ad_, N);
  gat_aggregate<false, true><<<nb4, 256, 0, stream>>>(rowstart, csr, as_, ad_,
                                                      xb, nullptr, aggx, N);
  {
    dim3 g((N + 63) / 64, HID / 64);
    gemm_mfma<HID, IN, true><<<g, 256, 0, stream>>>(aggx, Wp1, out1, N, b1);
  }

  // ---- layer 2: scores from out1, GEMM, aggregate h2 (+bias+ReLU) ----
  alpha2<<<nb4, 256, 0, stream>>>(out1, wa + 256, wa + 512, as_, ad_, N);
  {
    dim3 g((N + 63) / 64, OUT / 64);
    gemm_mfma<OUT, HID, false><<<g, 256, 0, stream>>>(out1, Wp2, h2, N, nullptr);
  }
  gat_aggregate<true, false><<<nb4, 256, 0, stream>>>(rowstart, csr, as_, ad_,
                                                      h2, b2, out, N);
}

// Round 7
// 199.331 us; speedup vs baseline: 19.3289x; 1.0360x over previous
//
#include <hip/hip_runtime.h>
#include <hip/hip_bf16.h>
#include <float.h>
#include <stdint.h>

#define NEG_SLOPE 0.2f

typedef __attribute__((ext_vector_type(8))) short short8;
typedef __attribute__((ext_vector_type(4))) float f32x4;

__device__ inline float b2f(unsigned short u) {
  return __uint_as_float((unsigned int)u << 16);
}
__device__ inline unsigned short f2b(float f) {
  unsigned int u = __float_as_uint(f);
  return (unsigned short)((u + 0x7FFF + ((u >> 16) & 1)) >> 16);
}
__device__ inline float leaky(float e) { return e >= 0.f ? e : NEG_SLOPE * e; }

// ---------------------------------------------------------------------------
// int32/int64 edge_index detection: int64 values < 50000 => odd words zero.
// ---------------------------------------------------------------------------
__global__ void detect_idx64_kernel(const void* ei, int* flag) {
  const int* p = (const int*)ei;
  int lane = threadIdx.x & 63;
  unsigned long long b = __ballot(p[2 * lane + 1] != 0);
  if (threadIdx.x == 0) *flag = (b == 0ull) ? 1 : 0;
}

__device__ inline int load_idx(const void* ei, long long pos, int is64) {
  if (is64) return (int)((const long long*)ei)[pos];
  return ((const int*)ei)[pos];
}

// ===========================================================================
// CSR build, XCD-ownership version (bucket = dst>>7, one block owns a
// bucket's csr region => no cross-XCD line bouncing).
// ===========================================================================
__global__ __launch_bounds__(256) void bucket_hist_kernel(
    const void* __restrict__ ei, const int* __restrict__ flag64, int E,
    unsigned int* __restrict__ bhist) {
  __shared__ int lh[512];
  int t = threadIdx.x;
  lh[t] = 0; lh[t + 256] = 0;
  __syncthreads();
  const int is64 = *flag64;
  const long long base = (long long)blockIdx.x * 2048;
#pragma unroll
  for (int i = 0; i < 8; ++i) {
    long long j = base + t + i * 256;
    if (j < E) {
      int d = load_idx(ei, (long long)E + j, is64);
      atomicAdd(&lh[d >> 7], 1);
    }
  }
  __syncthreads();
  if (lh[t]) atomicAdd(&bhist[t], (unsigned)lh[t]);
  if (lh[t + 256]) atomicAdd(&bhist[t + 256], (unsigned)lh[t + 256]);
}

__global__ void scan_buckets(const unsigned int* __restrict__ bhist,
                             int* __restrict__ bucket_base,
                             int* __restrict__ bcursor) {
  __shared__ int h[512];
  int t = threadIdx.x;
  h[t] = (int)bhist[t];
  h[t + 256] = (int)bhist[t + 256];
  __syncthreads();
  for (int off = 1; off < 512; off <<= 1) {
    int v0 = (t >= off) ? h[t - off] : 0;
    int v1 = h[t + 256 - off];
    __syncthreads();
    h[t] += v0;
    h[t + 256] += v1;
    __syncthreads();
  }
  int e0 = (t == 0) ? 0 : h[t - 1];
  int e1 = h[t + 255];
  bucket_base[t] = e0; bcursor[t] = e0;
  bucket_base[t + 256] = e1; bcursor[t + 256] = e1;
}

__global__ __launch_bounds__(256) void bin_edges(
    const void* __restrict__ ei, const int* __restrict__ flag64, int E,
    int* __restrict__ bcursor, unsigned int* __restrict__ binned) {
  __shared__ int hist[512];
  __shared__ int scn[512];
  __shared__ int gb[512];
  __shared__ unsigned int stage[2048];
  int t = threadIdx.x;
  hist[t] = 0; hist[t + 256] = 0;
  __syncthreads();
  const int is64 = *flag64;
  const long long base = (long long)blockIdx.x * 2048;
  const int cblk = (int)min((long long)2048, (long long)E - base);
  int sv[8];
  short bk[8], rk[8];
#pragma unroll
  for (int i = 0; i < 8; ++i) {
    int k = t + i * 256;
    if (k < cblk) {
      long long j = base + k;
      int s = load_idx(ei, j, is64);
      int d = load_idx(ei, (long long)E + j, is64);
      int b = d >> 7;
      bk[i] = (short)b;
      sv[i] = (s << 7) | (d & 127);
      rk[i] = (short)atomicAdd(&hist[b], 1);
    } else {
      bk[i] = -1;
    }
  }
  __syncthreads();
  scn[t] = hist[t]; scn[t + 256] = hist[t + 256];
  __syncthreads();
  for (int off = 1; off < 512; off <<= 1) {
    int v0 = (t >= off) ? scn[t - off] : 0;
    int v1 = scn[t + 256 - off];
    __syncthreads();
    scn[t] += v0;
    scn[t + 256] += v1;
    __syncthreads();
  }
  int c0 = hist[t], c1 = hist[t + 256];
  int l0 = scn[t] - c0, l1 = scn[t + 256] - c1;
  if (c0) gb[t] = atomicAdd(&bcursor[t], c0);
  if (c1) gb[t + 256] = atomicAdd(&bcursor[t + 256], c1);
  scn[t] = l0; scn[t + 256] = l1;
  __syncthreads();
#pragma unroll
  for (int i = 0; i < 8; ++i) {
    if (bk[i] >= 0)
      stage[scn[bk[i]] + rk[i]] = ((unsigned)(int)bk[i] << 23) | (unsigned)sv[i];
  }
  __syncthreads();
#pragma unroll
  for (int i = 0; i < 8; ++i) {
    int k = t + i * 256;
    if (k < cblk) {
      unsigned w = stage[k];
      int b = w >> 23;
      binned[gb[b] + (k - scn[b])] = w;
    }
  }
}

__global__ __launch_bounds__(256) void place_csr(
    const unsigned int* __restrict__ binned,
    const int* __restrict__ bucket_base, int* __restrict__ rowstart,
    unsigned short* __restrict__ csr, int Nn, int E) {
  __shared__ int cnt[128], deg0[128], cur[128];
  int t = threadIdx.x;
  int b = blockIdx.x;
  if (t < 128) cnt[t] = 0;
  __syncthreads();
  const int rbeg = bucket_base[b], rend = bucket_base[b + 1];
  for (int k = rbeg + t; k < rend; k += 256)
    atomicAdd(&cnt[binned[k] & 127], 1);
  __syncthreads();
  if (t < 128) deg0[t] = cnt[t];
  __syncthreads();
  for (int off = 1; off < 128; off <<= 1) {
    int v = (t >= off && t < 128) ? cnt[t - off] : 0;
    __syncthreads();
    if (t < 128) cnt[t] += v;
    __syncthreads();
  }
  const int node0 = b << 7;
  if (t < 128) {
    int start = rbeg + cnt[t] - deg0[t];
    int node = node0 + t;
    if (node < Nn) rowstart[node] = start;
    cur[t] = start;
  }
  if (b == 0 && t == 0) rowstart[Nn] = E;
  __syncthreads();
  for (int k = rbeg + t; k < rend; k += 256) {
    unsigned w = binned[k];
    int pos = atomicAdd(&cur[w & 127], 1);
    csr[pos] = (unsigned short)((w >> 7) & 0xFFFF);
  }
}

// ---------------------------------------------------------------------------
// One-shot weight prep: pack W1/W2 to fragment layout + 4 matvecs
// wa[768] = {W1@a1s, W1@a1d, W2@a2s, W2@a2d}
// ---------------------------------------------------------------------------
__global__ __launch_bounds__(256) void prep_weights(
    const float* __restrict__ W1, const float* __restrict__ W2,
    const float* __restrict__ a1s, const float* __restrict__ a1d,
    const float* __restrict__ a2s, const float* __restrict__ a2d,
    unsigned short* __restrict__ Wp1, unsigned short* __restrict__ Wp2,
    float* __restrict__ wa) {
  int b = blockIdx.x;
  int t = threadIdx.x;
  if (b < 128) {
    int i = b * 256 + t;
    int k = i >> 8, n = i & 255;
    Wp1[(((k >> 3) * 256 + n) << 3) + (k & 7)] = f2b(W1[i]);
  } else if (b < 256) {
    int i = (b - 128) * 256 + t;
    int k = i >> 7, n = i & 127;
    Wp2[(((k >> 3) * 128 + n) << 3) + (k & 7)] = f2b(W2[i]);
  } else {
    int o = (b - 256) * 256 + t;
    float s = 0.f;
    if (o < 128) {
      for (int n = 0; n < 256; ++n) s += W1[o * 256 + n] * a1s[n];
    } else if (o < 256) {
      int k = o - 128;
      for (int n = 0; n < 256; ++n) s += W1[k * 256 + n] * a1d[n];
    } else if (o < 512) {
      int k = o - 256;
      for (int n = 0; n < 128; ++n) s += W2[k * 128 + n] * a2s[n];
    } else {
      int k = o - 512;
      for (int n = 0; n < 128; ++n) s += W2[k * 128 + n] * a2d[n];
    }
    wa[o] = s;
  }
}

// ---------------------------------------------------------------------------
// Layer-1 scores + bf16 cast of x (one wave per node, fp32 x [N,128])
// ---------------------------------------------------------------------------
__global__ __launch_bounds__(256) void alpha1_cast(
    const float* __restrict__ x, const float* __restrict__ wa,
    unsigned short* __restrict__ xb, float* __restrict__ as_out,
    float* __restrict__ ad_out, int Nn) {
  int node = blockIdx.x * 4 + (threadIdx.x >> 6);
  int lane = threadIdx.x & 63;
  if (node >= Nn) return;
  float2 v = *(const float2*)(x + (long long)node * 128 + lane * 2);
  float s1 = v.x * wa[lane * 2] + v.y * wa[lane * 2 + 1];
  float s2 = v.x * wa[128 + lane * 2] + v.y * wa[128 + lane * 2 + 1];
  unsigned int packed = (unsigned int)f2b(v.x) | ((unsigned int)f2b(v.y) << 16);
  *(unsigned int*)(xb + (long long)node * 128 + lane * 2) = packed;
#pragma unroll
  for (int off = 32; off > 0; off >>= 1) {
    s1 += __shfl_down(s1, off);
    s2 += __shfl_down(s2, off);
  }
  if (lane == 0) {
    as_out[node] = s1;
    ad_out[node] = s2;
  }
}

// ---------------------------------------------------------------------------
// MFMA bf16 GEMM, fragments direct from global. Optional bias+ReLU epilogue.
// SCORES (deterministic, atomic-free): the A-fragments of this GEMM stream
// every element of A; accumulate per-lane partial dots of A-rows with
// was/wad over the K dim, shfl-reduce across the 4 k-groups holding each
// row, and have blockIdx.y==0 blocks store s_as/s_ad. Single writer per row.
// ---------------------------------------------------------------------------
template <int Nn, int Kk, bool BIAS_RELU, bool SCORES>
__global__ __launch_bounds__(256) void gemm_mfma(
    const unsigned short* __restrict__ A, const unsigned short* __restrict__ Bp,
    unsigned short* __restrict__ C, int M, const float* __restrict__ bias,
    const float* __restrict__ was, const float* __restrict__ wad,
    float* __restrict__ s_as, float* __restrict__ s_ad) {
  const int l = threadIdx.x & 63;
  const int wm = threadIdx.x >> 6;
  const int bm = blockIdx.x * 64;
  const int bn = blockIdx.y * 64;
  const int arow = bm + wm * 16 + (l & 15);
  const int kg = l >> 4;

  f32x4 acc[4];
#pragma unroll
  for (int nt = 0; nt < 4; ++nt) acc[nt] = (f32x4){0.f, 0.f, 0.f, 0.f};

  const bool arow_ok = (arow < M);
  const bool do_scores = SCORES && (blockIdx.y == 0);
  float ps = 0.f, pd = 0.f;
#pragma unroll
  for (int kk = 0; kk < Kk; kk += 32) {
    short8 afrag;
    if (arow_ok)
      afrag = *(const short8*)(A + (long long)arow * Kk + kk + kg * 8);
    else
      afrag = (short8){0, 0, 0, 0, 0, 0, 0, 0};
    if (SCORES) {
      if (do_scores) {
        const int kb0 = kk + kg * 8;
#pragma unroll
        for (int i = 0; i < 8; ++i) {
          float v = b2f((unsigned short)afrag[i]);
          ps += v * was[kb0 + i];
          pd += v * wad[kb0 + i];
        }
      }
    }
    const int kb = (kk >> 3) + kg;
#pragma unroll
    for (int nt = 0; nt < 4; ++nt) {
      short8 bfrag = *(const short8*)(Bp + (((long long)kb * Nn + bn + nt * 16 +
                                             (l & 15))
                                            << 3));
      acc[nt] = __builtin_amdgcn_mfma_f32_16x16x32_bf16(afrag, bfrag, acc[nt],
                                                        0, 0, 0);
    }
  }
  if (SCORES) {
    if (do_scores) {
      ps += __shfl_xor(ps, 16); ps += __shfl_xor(ps, 32);
      pd += __shfl_xor(pd, 16); pd += __shfl_xor(pd, 32);
      if (l < 16 && arow_ok) {
        s_as[arow] = ps;
        s_ad[arow] = pd;
      }
    }
  }
#pragma unroll
  for (int nt = 0; nt < 4; ++nt) {
    const int col = bn + nt * 16 + (l & 15);
    float bv = BIAS_RELU ? bias[col] : 0.f;
#pragma unroll
    for (int r = 0; r < 4; ++r) {
      const int row = bm + wm * 16 + (l >> 4) * 4 + r;
      if (row < M) {
        float v = acc[nt][r];
        if (BIAS_RELU) v = fmaxf(v + bv, 0.f);
        C[(long long)row * Nn + col] = f2b(v);
      }
    }
  }
}

// ---------------------------------------------------------------------------
// Single-pass flash-style softmax + gather-aggregate (+ optional bias+ReLU).
// One wave per node: 4 edge groups x 16 lanes; each group keeps online
// (m, sum, acc[8]) with defer-max threshold 8 (rescale rarely fires).
// ---------------------------------------------------------------------------
template <bool BIAS_RELU, bool OUT_BF16>
__global__ __launch_bounds__(256) void gat_aggregate(
    const int* __restrict__ rowstart, const unsigned short* __restrict__ csr,
    const float* __restrict__ as, const float* __restrict__ ad,
    const unsigned short* __restrict__ h, const float* __restrict__ bias,
    void* __restrict__ outp, int Nn) {
  constexpr int F = 128;
  int node = blockIdx.x * 4 + (threadIdx.x >> 6);
  int lane = threadIdx.x & 63;
  if (node >= Nn) return;
  const int beg = rowstart[node];
  const int end = rowstart[node + 1];
  const float adn = ad[node];
  const int grp = lane >> 4;
  const int hl = lane & 15;
  const int f0 = hl * 8;

  float m, sg;
  float acc[8];
  if (grp == 0) {  // self-loop seeds group 0
    m = leaky(as[node] + adn);
    sg = 1.f;
    short8 v = *(const short8*)(h + (long long)node * F + f0);
#pragma unroll
    for (int j = 0; j < 8; ++j) acc[j] = b2f((unsigned short)v[j]);
  } else {
    m = -3.4e38f;
    sg = 0.f;
#pragma unroll
    for (int j = 0; j < 8; ++j) acc[j] = 0.f;
  }

  for (int t = beg + grp; t < end; t += 4) {
    int s = csr[t];
    float e = leaky(as[s] + adn);
    if (e > m + 8.f) {  // deferred-max rescale (rare)
      float sc = __expf(m - e);
      sg *= sc;
#pragma unroll
      for (int j = 0; j < 8; ++j) acc[j] *= sc;
      m = e;
    }
    float p = __expf(e - m);
    sg += p;
    short8 v = *(const short8*)(h + (long long)s * F + f0);
#pragma unroll
    for (int j = 0; j < 8; ++j) acc[j] += p * b2f((unsigned short)v[j]);
  }

  // merge the 4 groups (pairwise, with max alignment)
#pragma unroll
  for (int off = 16; off <= 32; off <<= 1) {
    float mo = __shfl_xor(m, off);
    float so = __shfl_xor(sg, off);
    float mn = fmaxf(m, mo);
    float c0 = __expf(m - mn);
    float c1 = __expf(mo - mn);
    sg = sg * c0 + so * c1;
#pragma unroll
    for (int j = 0; j < 8; ++j) {
      float ao = __shfl_xor(acc[j], off);
      acc[j] = acc[j] * c0 + ao * c1;
    }
    m = mn;
  }
  const float inv = 1.f / (sg + 1e-16f);

  if (lane < 16) {
#pragma unroll
    for (int j = 0; j < 8; ++j) {
      acc[j] *= inv;
      if (BIAS_RELU) acc[j] = fmaxf(acc[j] + bias[f0 + j], 0.f);
    }
    if (OUT_BF16) {
      short8 o;
#pragma unroll
      for (int j = 0; j < 8; ++j) o[j] = (short)f2b(acc[j]);
      *(short8*)((unsigned short*)outp + (long long)node * F + f0) = o;
    } else {
      float4 o0 = {acc[0], acc[1], acc[2], acc[3]};
      float4 o1 = {acc[4], acc[5], acc[6], acc[7]};
      float* orow = (float*)outp + (long long)node * F + f0;
      *(float4*)(orow) = o0;
      *(float4*)(orow + 4) = o1;
    }
  }
}

extern "C" void kernel_launch(void* const* d_in, const int* in_sizes, int n_in,
                              void* d_out, int out_size, void* d_ws,
                              size_t ws_size, hipStream_t stream) {
  const float* x      = (const float*)d_in[0];
  const void*  ei     = d_in[1];
  const float* W1     = (const float*)d_in[2];
  const float* a1_src = (const float*)d_in[3];
  const float* a1_dst = (const float*)d_in[4];
  const float* b1     = (const float*)d_in[5];
  const float* W2     = (const float*)d_in[6];
  const float* a2_src = (const float*)d_in[7];
  const float* a2_dst = (const float*)d_in[8];
  const float* b2     = (const float*)d_in[9];
  float* out = (float*)d_out;

  const int N = 50000, E = 800000, IN = 128, HID = 256, OUT = 128;
  const int NBLK_E = (E + 2047) / 2048;
  const int NB = (N + 127) >> 7;

  char* ws = (char*)d_ws;
  size_t off = 0;
  auto carve = [&](size_t bytes) -> void* {
    void* p = ws + off;
    off = (off + bytes + 255) & ~(size_t)255;
    return p;
  };
  unsigned short* xb     = (unsigned short*)carve((size_t)N * IN * 2);
  unsigned short* aggx   = (unsigned short*)carve((size_t)N * IN * 2);
  unsigned short* out1   = (unsigned short*)carve((size_t)N * HID * 2);
  unsigned short* h2     = (unsigned short*)carve((size_t)N * OUT * 2);
  unsigned short* Wp1    = (unsigned short*)carve((size_t)IN * HID * 2);
  unsigned short* Wp2    = (unsigned short*)carve((size_t)HID * OUT * 2);
  float*          wa     = (float*)carve(768 * 4);
  unsigned int*   binned = (unsigned int*)carve((size_t)E * 4);
  unsigned short* csr    = (unsigned short*)carve((size_t)E * 2);
  unsigned int*   bhist  = (unsigned int*)carve(512 * 4);
  int*            bbase  = (int*)carve(513 * 4);
  int*            bcur   = (int*)carve(512 * 4);
  int*            rowstart = (int*)carve((size_t)(N + 1) * 4);
  float*          as_    = (float*)carve((size_t)N * 4);
  float*          ad_    = (float*)carve((size_t)N * 4);
  float*          as2_   = (float*)carve((size_t)N * 4);
  float*          ad2_   = (float*)carve((size_t)N * 4);
  int*            flag64 = (int*)carve(256);
  (void)ws_size; (void)in_sizes; (void)n_in; (void)out_size;

  hipMemsetAsync(bhist, 0, 512 * 4, stream);
  detect_idx64_kernel<<<1, 64, 0, stream>>>(ei, flag64);

  // ---- CSR build (bucketed, XCD-exclusive writes) ----
  bucket_hist_kernel<<<NBLK_E, 256, 0, stream>>>(ei, flag64, E, bhist);
  scan_buckets<<<1, 256, 0, stream>>>(bhist, bbase, bcur);
  bin_edges<<<NBLK_E, 256, 0, stream>>>(ei, flag64, E, bcur, binned);
  place_csr<<<NB, 256, 0, stream>>>(binned, bbase, rowstart, csr, N, E);

  // ---- weights ----
  prep_weights<<<259, 256, 0, stream>>>(W1, W2, a1_src, a1_dst, a2_src, a2_dst,
                                        Wp1, Wp2, wa);

  const int nb4 = (N + 3) / 4;

  // ---- layer 1: scores from x, aggregate x, GEMM(+bias+ReLU) ----
  alpha1_cast<<<nb4, 256, 0, stream>>>(x, wa, xb, as_, ad_, N);
  gat_aggregate<false, true><<<nb4, 256, 0, stream>>>(rowstart, csr, as_, ad_,
                                                      xb, nullptr, aggx, N);
  {
    dim3 g((N + 63) / 64, HID / 64);
    gemm_mfma<HID, IN, true, false><<<g, 256, 0, stream>>>(
        aggx, Wp1, out1, N, b1, nullptr, nullptr, nullptr, nullptr);
  }

  // ---- layer 2: GEMM (+deterministic fused scores), aggregate ----
  {
    dim3 g((N + 63) / 64, OUT / 64);
    gemm_mfma<OUT, HID, false, true><<<g, 256, 0, stream>>>(
        out1, Wp2, h2, N, nullptr, wa + 256, wa + 512, as2_, ad2_);
  }
  gat_aggregate<true, false><<<nb4, 256, 0, stream>>>(rowstart, csr, as2_,
                                                      ad2_, h2, b2, out, N);
}

// Round 8
// 171.925 us; speedup vs baseline: 22.4101x; 1.1594x over previous
//
#include <hip/hip_runtime.h>
#include <hip/hip_bf16.h>
#include <float.h>
#include <stdint.h>

#define NEG_SLOPE 0.2f

typedef __attribute__((ext_vector_type(8))) short short8;
typedef __attribute__((ext_vector_type(4))) float f32x4;

#define BSTRIDE 3072  // padded per-bucket capacity (mean 2048, 22+ sigma slack)

__device__ inline float b2f(unsigned short u) {
  return __uint_as_float((unsigned int)u << 16);
}
__device__ inline unsigned short f2b(float f) {
  unsigned int u = __float_as_uint(f);
  return (unsigned short)((u + 0x7FFF + ((u >> 16) & 1)) >> 16);
}
__device__ inline float leaky(float e) { return e >= 0.f ? e : NEG_SLOPE * e; }
__device__ inline float blo(unsigned int w) {
  return __uint_as_float(w << 16);
}
__device__ inline float bhi(unsigned int w) {
  return __uint_as_float(w & 0xFFFF0000u);
}

// ---------------------------------------------------------------------------
// int32/int64 edge_index detection: int64 values < 50000 => odd words zero.
// ---------------------------------------------------------------------------
__global__ void detect_idx64_kernel(const void* ei, int* flag) {
  const int* p = (const int*)ei;
  int lane = threadIdx.x & 63;
  unsigned long long b = __ballot(p[2 * lane + 1] != 0);
  if (threadIdx.x == 0) *flag = (b == 0ull) ? 1 : 0;
}

__device__ inline int load_idx(const void* ei, long long pos, int is64) {
  if (is64) return (int)((const long long*)ei)[pos];
  return ((const int*)ei)[pos];
}

// ===========================================================================
// CSR build, one-pass bucketed version. bucket = dst>>7 (128 nodes each).
// bin_edges: block-local radix by bucket -> reserve via one atomic per
//            bucket -> coalesced flush into slack-padded binned regions.
// place_csr: one block owns one bucket: per-node degree + LDS scan ->
//            rowbe {beg,end}, LDS-cursor scatter csr[pos]=src (ushort).
//            All writes to a bucket's region come from ONE block.
// ===========================================================================
__global__ __launch_bounds__(256) void bin_edges(
    const void* __restrict__ ei, const int* __restrict__ flag64, int E,
    int* __restrict__ bcursor, unsigned int* __restrict__ binned) {
  __shared__ int hist[512];
  __shared__ int scn[512];
  __shared__ int gb[512];
  __shared__ unsigned int stage[2048];
  int t = threadIdx.x;
  hist[t] = 0; hist[t + 256] = 0;
  __syncthreads();
  const int is64 = *flag64;
  const long long base = (long long)blockIdx.x * 2048;
  const int cblk = (int)min((long long)2048, (long long)E - base);
  int sv[8];
  short bk[8], rk[8];
#pragma unroll
  for (int i = 0; i < 8; ++i) {
    int k = t + i * 256;
    if (k < cblk) {
      long long j = base + k;
      int s = load_idx(ei, j, is64);
      int d = load_idx(ei, (long long)E + j, is64);
      int b = d >> 7;
      bk[i] = (short)b;
      sv[i] = (s << 7) | (d & 127);
      rk[i] = (short)atomicAdd(&hist[b], 1);
    } else {
      bk[i] = -1;
    }
  }
  __syncthreads();
  scn[t] = hist[t]; scn[t + 256] = hist[t + 256];
  __syncthreads();
  for (int off = 1; off < 512; off <<= 1) {
    int v0 = (t >= off) ? scn[t - off] : 0;
    int v1 = scn[t + 256 - off];
    __syncthreads();
    scn[t] += v0;
    scn[t + 256] += v1;
    __syncthreads();
  }
  int c0 = hist[t], c1 = hist[t + 256];
  int l0 = scn[t] - c0, l1 = scn[t + 256] - c1;
  if (c0) gb[t] = atomicAdd(&bcursor[t], c0);
  if (c1) gb[t + 256] = atomicAdd(&bcursor[t + 256], c1);
  scn[t] = l0; scn[t + 256] = l1;
  __syncthreads();
#pragma unroll
  for (int i = 0; i < 8; ++i) {
    if (bk[i] >= 0)
      stage[scn[bk[i]] + rk[i]] = ((unsigned)(int)bk[i] << 23) | (unsigned)sv[i];
  }
  __syncthreads();
#pragma unroll
  for (int i = 0; i < 8; ++i) {
    int k = t + i * 256;
    if (k < cblk) {
      unsigned w = stage[k];
      int b = w >> 23;
      binned[(long long)b * BSTRIDE + gb[b] + (k - scn[b])] = w;
    }
  }
}

__global__ __launch_bounds__(256) void place_csr(
    const unsigned int* __restrict__ binned, const int* __restrict__ bcursor,
    int2* __restrict__ rowbe, unsigned short* __restrict__ csr, int Nn) {
  __shared__ int cnt[128], deg0[128], cur[128];
  int t = threadIdx.x;
  int b = blockIdx.x;
  if (t < 128) cnt[t] = 0;
  __syncthreads();
  const int rbeg = b * BSTRIDE;
  const int rend = rbeg + bcursor[b];
  for (int k = rbeg + t; k < rend; k += 256)
    atomicAdd(&cnt[binned[k] & 127], 1);
  __syncthreads();
  if (t < 128) deg0[t] = cnt[t];
  __syncthreads();
  for (int off = 1; off < 128; off <<= 1) {
    int v = (t >= off && t < 128) ? cnt[t - off] : 0;
    __syncthreads();
    if (t < 128) cnt[t] += v;
    __syncthreads();
  }
  const int node0 = b << 7;
  if (t < 128) {
    int start = rbeg + cnt[t] - deg0[t];
    int node = node0 + t;
    if (node < Nn) rowbe[node] = make_int2(start, start + deg0[t]);
    cur[t] = start;
  }
  __syncthreads();
  for (int k = rbeg + t; k < rend; k += 256) {
    unsigned w = binned[k];
    int pos = atomicAdd(&cur[w & 127], 1);
    csr[pos] = (unsigned short)((w >> 7) & 0xFFFF);
  }
}

// ---------------------------------------------------------------------------
// One-shot weight prep: pack W1/W2 to fragment layout + 4 matvecs
// wa[768] = {W1@a1s, W1@a1d, W2@a2s, W2@a2d}
// ---------------------------------------------------------------------------
__global__ __launch_bounds__(256) void prep_weights(
    const float* __restrict__ W1, const float* __restrict__ W2,
    const float* __restrict__ a1s, const float* __restrict__ a1d,
    const float* __restrict__ a2s, const float* __restrict__ a2d,
    unsigned short* __restrict__ Wp1, unsigned short* __restrict__ Wp2,
    float* __restrict__ wa) {
  int b = blockIdx.x;
  int t = threadIdx.x;
  if (b < 128) {
    int i = b * 256 + t;
    int k = i >> 8, n = i & 255;
    Wp1[(((k >> 3) * 256 + n) << 3) + (k & 7)] = f2b(W1[i]);
  } else if (b < 256) {
    int i = (b - 128) * 256 + t;
    int k = i >> 7, n = i & 127;
    Wp2[(((k >> 3) * 128 + n) << 3) + (k & 7)] = f2b(W2[i]);
  } else {
    int o = (b - 256) * 256 + t;
    float s = 0.f;
    if (o < 128) {
      for (int n = 0; n < 256; ++n) s += W1[o * 256 + n] * a1s[n];
    } else if (o < 256) {
      int k = o - 128;
      for (int n = 0; n < 256; ++n) s += W1[k * 256 + n] * a1d[n];
    } else if (o < 512) {
      int k = o - 256;
      for (int n = 0; n < 128; ++n) s += W2[k * 128 + n] * a2s[n];
    } else {
      int k = o - 512;
      for (int n = 0; n < 128; ++n) s += W2[k * 128 + n] * a2d[n];
    }
    wa[o] = s;
  }
}

// ---------------------------------------------------------------------------
// Layer-1 scores + bf16 cast of x (one wave per node, fp32 x [N,128])
// ---------------------------------------------------------------------------
__global__ __launch_bounds__(256) void alpha1_cast(
    const float* __restrict__ x, const float* __restrict__ wa,
    unsigned short* __restrict__ xb, float* __restrict__ as_out,
    float* __restrict__ ad_out, int Nn) {
  int node = blockIdx.x * 4 + (threadIdx.x >> 6);
  int lane = threadIdx.x & 63;
  if (node >= Nn) return;
  float2 v = *(const float2*)(x + (long long)node * 128 + lane * 2);
  float s1 = v.x * wa[lane * 2] + v.y * wa[lane * 2 + 1];
  float s2 = v.x * wa[128 + lane * 2] + v.y * wa[128 + lane * 2 + 1];
  unsigned int packed = (unsigned int)f2b(v.x) | ((unsigned int)f2b(v.y) << 16);
  *(unsigned int*)(xb + (long long)node * 128 + lane * 2) = packed;
#pragma unroll
  for (int off = 32; off > 0; off >>= 1) {
    s1 += __shfl_down(s1, off);
    s2 += __shfl_down(s2, off);
  }
  if (lane == 0) {
    as_out[node] = s1;
    ad_out[node] = s2;
  }
}

// ---------------------------------------------------------------------------
// MFMA bf16 GEMM, fragments direct from global. Optional bias+ReLU epilogue.
// SCORES (deterministic, atomic-free): per-lane partial dots of A-rows with
// was/wad over K, shfl-reduce across the 4 k-groups, blockIdx.y==0 stores.
// ---------------------------------------------------------------------------
template <int Nn, int Kk, bool BIAS_RELU, bool SCORES>
__global__ __launch_bounds__(256) void gemm_mfma(
    const unsigned short* __restrict__ A, const unsigned short* __restrict__ Bp,
    unsigned short* __restrict__ C, int M, const float* __restrict__ bias,
    const float* __restrict__ was, const float* __restrict__ wad,
    float* __restrict__ s_as, float* __restrict__ s_ad) {
  const int l = threadIdx.x & 63;
  const int wm = threadIdx.x >> 6;
  const int bm = blockIdx.x * 64;
  const int bn = blockIdx.y * 64;
  const int arow = bm + wm * 16 + (l & 15);
  const int kg = l >> 4;

  f32x4 acc[4];
#pragma unroll
  for (int nt = 0; nt < 4; ++nt) acc[nt] = (f32x4){0.f, 0.f, 0.f, 0.f};

  const bool arow_ok = (arow < M);
  const bool do_scores = SCORES && (blockIdx.y == 0);
  float ps = 0.f, pd = 0.f;
#pragma unroll
  for (int kk = 0; kk < Kk; kk += 32) {
    short8 afrag;
    if (arow_ok)
      afrag = *(const short8*)(A + (long long)arow * Kk + kk + kg * 8);
    else
      afrag = (short8){0, 0, 0, 0, 0, 0, 0, 0};
    if (SCORES) {
      if (do_scores) {
        const int kb0 = kk + kg * 8;
#pragma unroll
        for (int i = 0; i < 8; ++i) {
          float v = b2f((unsigned short)afrag[i]);
          ps += v * was[kb0 + i];
          pd += v * wad[kb0 + i];
        }
      }
    }
    const int kb = (kk >> 3) + kg;
#pragma unroll
    for (int nt = 0; nt < 4; ++nt) {
      short8 bfrag = *(const short8*)(Bp + (((long long)kb * Nn + bn + nt * 16 +
                                             (l & 15))
                                            << 3));
      acc[nt] = __builtin_amdgcn_mfma_f32_16x16x32_bf16(afrag, bfrag, acc[nt],
                                                        0, 0, 0);
    }
  }
  if (SCORES) {
    if (do_scores) {
      ps += __shfl_xor(ps, 16); ps += __shfl_xor(ps, 32);
      pd += __shfl_xor(pd, 16); pd += __shfl_xor(pd, 32);
      if (l < 16 && arow_ok) {
        s_as[arow] = ps;
        s_ad[arow] = pd;
      }
    }
  }
#pragma unroll
  for (int nt = 0; nt < 4; ++nt) {
    const int col = bn + nt * 16 + (l & 15);
    float bv = BIAS_RELU ? bias[col] : 0.f;
#pragma unroll
    for (int r = 0; r < 4; ++r) {
      const int row = bm + wm * 16 + (l >> 4) * 4 + r;
      if (row < M) {
        float v = acc[nt][r];
        if (BIAS_RELU) v = fmaxf(v + bv, 0.f);
        C[(long long)row * Nn + col] = f2b(v);
      }
    }
  }
}

// ---------------------------------------------------------------------------
// Single-pass flash-style softmax + gather-aggregate (+ optional bias+ReLU).
// One wave per node, 4 groups x 16 lanes. Each group takes a CONTIGUOUS
// chunk of the edge list and processes 4 edges per iteration: 4 independent
// 16B h-row loads in flight per lane (MLP vs latency-bound single load).
// Shared deferred-max (threshold 8) keeps the rescale off the hot path.
// ---------------------------------------------------------------------------
template <bool BIAS_RELU, bool OUT_BF16>
__global__ __launch_bounds__(256) void gat_aggregate(
    const int2* __restrict__ rowbe, const unsigned short* __restrict__ csr,
    const float* __restrict__ as, const float* __restrict__ ad,
    const unsigned short* __restrict__ h, const float* __restrict__ bias,
    void* __restrict__ outp, int Nn) {
  constexpr int F = 128;
  int node = blockIdx.x * 4 + (threadIdx.x >> 6);
  int lane = threadIdx.x & 63;
  if (node >= Nn) return;
  const int2 be = rowbe[node];
  const int beg = be.x, end = be.y;
  const int deg = end - beg;
  const float adn = ad[node];
  const int grp = lane >> 4;
  const int hl = lane & 15;
  const int f0 = hl * 8;

  const int chunk = (deg + 3) >> 2;
  int t = beg + grp * chunk;
  const int gend = min(t + chunk, end);

  float m, sg;
  float acc[8];
  if (grp == 0) {  // self-loop seeds group 0
    m = leaky(as[node] + adn);
    sg = 1.f;
    uint4 w = *(const uint4*)(h + (long long)node * F + f0);
    acc[0] = blo(w.x); acc[1] = bhi(w.x);
    acc[2] = blo(w.y); acc[3] = bhi(w.y);
    acc[4] = blo(w.z); acc[5] = bhi(w.z);
    acc[6] = blo(w.w); acc[7] = bhi(w.w);
  } else {
    m = -3.4e38f;
    sg = 0.f;
#pragma unroll
    for (int j = 0; j < 8; ++j) acc[j] = 0.f;
  }

  // unroll-4 main loop: batch 4 edges, issue all 4 h loads before use
  for (; t + 4 <= gend; t += 4) {
    int s0 = csr[t], s1 = csr[t + 1], s2 = csr[t + 2], s3 = csr[t + 3];
    uint4 w0 = *(const uint4*)(h + (long long)s0 * F + f0);
    uint4 w1 = *(const uint4*)(h + (long long)s1 * F + f0);
    uint4 w2 = *(const uint4*)(h + (long long)s2 * F + f0);
    uint4 w3 = *(const uint4*)(h + (long long)s3 * F + f0);
    float e0 = leaky(as[s0] + adn);
    float e1 = leaky(as[s1] + adn);
    float e2 = leaky(as[s2] + adn);
    float e3 = leaky(as[s3] + adn);
    float em = fmaxf(fmaxf(e0, e1), fmaxf(e2, e3));
    if (em > m + 8.f) {  // deferred-max rescale (rare)
      float sc = __expf(m - em);
      sg *= sc;
#pragma unroll
      for (int j = 0; j < 8; ++j) acc[j] *= sc;
      m = em;
    }
    float p0 = __expf(e0 - m), p1 = __expf(e1 - m);
    float p2 = __expf(e2 - m), p3 = __expf(e3 - m);
    sg += (p0 + p1) + (p2 + p3);
    acc[0] += p0 * blo(w0.x) + p1 * blo(w1.x) + p2 * blo(w2.x) + p3 * blo(w3.x);
    acc[1] += p0 * bhi(w0.x) + p1 * bhi(w1.x) + p2 * bhi(w2.x) + p3 * bhi(w3.x);
    acc[2] += p0 * blo(w0.y) + p1 * blo(w1.y) + p2 * blo(w2.y) + p3 * blo(w3.y);
    acc[3] += p0 * bhi(w0.y) + p1 * bhi(w1.y) + p2 * bhi(w2.y) + p3 * bhi(w3.y);
    acc[4] += p0 * blo(w0.z) + p1 * blo(w1.z) + p2 * blo(w2.z) + p3 * blo(w3.z);
    acc[5] += p0 * bhi(w0.z) + p1 * bhi(w1.z) + p2 * bhi(w2.z) + p3 * bhi(w3.z);
    acc[6] += p0 * blo(w0.w) + p1 * blo(w1.w) + p2 * blo(w2.w) + p3 * blo(w3.w);
    acc[7] += p0 * bhi(w0.w) + p1 * bhi(w1.w) + p2 * bhi(w2.w) + p3 * bhi(w3.w);
  }
  // tail
  for (; t < gend; ++t) {
    int s = csr[t];
    uint4 w = *(const uint4*)(h + (long long)s * F + f0);
    float e = leaky(as[s] + adn);
    if (e > m + 8.f) {
      float sc = __expf(m - e);
      sg *= sc;
#pragma unroll
      for (int j = 0; j < 8; ++j) acc[j] *= sc;
      m = e;
    }
    float p = __expf(e - m);
    sg += p;
    acc[0] += p * blo(w.x); acc[1] += p * bhi(w.x);
    acc[2] += p * blo(w.y); acc[3] += p * bhi(w.y);
    acc[4] += p * blo(w.z); acc[5] += p * bhi(w.z);
    acc[6] += p * blo(w.w); acc[7] += p * bhi(w.w);
  }

  // merge the 4 groups (pairwise, with max alignment)
#pragma unroll
  for (int off = 16; off <= 32; off <<= 1) {
    float mo = __shfl_xor(m, off);
    float so = __shfl_xor(sg, off);
    float mn = fmaxf(m, mo);
    float c0 = __expf(m - mn);
    float c1 = __expf(mo - mn);
    sg = sg * c0 + so * c1;
#pragma unroll
    for (int j = 0; j < 8; ++j) {
      float ao = __shfl_xor(acc[j], off);
      acc[j] = acc[j] * c0 + ao * c1;
    }
    m = mn;
  }
  const float inv = 1.f / (sg + 1e-16f);

  if (lane < 16) {
#pragma unroll
    for (int j = 0; j < 8; ++j) {
      acc[j] *= inv;
      if (BIAS_RELU) acc[j] = fmaxf(acc[j] + bias[f0 + j], 0.f);
    }
    if (OUT_BF16) {
      short8 o;
#pragma unroll
      for (int j = 0; j < 8; ++j) o[j] = (short)f2b(acc[j]);
      *(short8*)((unsigned short*)outp + (long long)node * F + f0) = o;
    } else {
      float4 o0 = {acc[0], acc[1], acc[2], acc[3]};
      float4 o1 = {acc[4], acc[5], acc[6], acc[7]};
      float* orow = (float*)outp + (long long)node * F + f0;
      *(float4*)(orow) = o0;
      *(float4*)(orow + 4) = o1;
    }
  }
}

extern "C" void kernel_launch(void* const* d_in, const int* in_sizes, int n_in,
                              void* d_out, int out_size, void* d_ws,
                              size_t ws_size, hipStream_t stream) {
  const float* x      = (const float*)d_in[0];
  const void*  ei     = d_in[1];
  const float* W1     = (const float*)d_in[2];
  const float* a1_src = (const float*)d_in[3];
  const float* a1_dst = (const float*)d_in[4];
  const float* b1     = (const float*)d_in[5];
  const float* W2     = (const float*)d_in[6];
  const float* a2_src = (const float*)d_in[7];
  const float* a2_dst = (const float*)d_in[8];
  const float* b2     = (const float*)d_in[9];
  float* out = (float*)d_out;

  const int N = 50000, E = 800000, IN = 128, HID = 256, OUT = 128;
  const int NBLK_E = (E + 2047) / 2048;
  const int NB = (N + 127) >> 7;

  char* ws = (char*)d_ws;
  size_t off = 0;
  auto carve = [&](size_t bytes) -> void* {
    void* p = ws + off;
    off = (off + bytes + 255) & ~(size_t)255;
    return p;
  };
  unsigned short* xb     = (unsigned short*)carve((size_t)N * IN * 2);
  unsigned short* aggx   = (unsigned short*)carve((size_t)N * IN * 2);
  unsigned short* out1   = (unsigned short*)carve((size_t)N * HID * 2);
  unsigned short* h2     = (unsigned short*)carve((size_t)N * OUT * 2);
  unsigned short* Wp1    = (unsigned short*)carve((size_t)IN * HID * 2);
  unsigned short* Wp2    = (unsigned short*)carve((size_t)HID * OUT * 2);
  float*          wa     = (float*)carve(768 * 4);
  unsigned int*   binned = (unsigned int*)carve((size_t)NB * BSTRIDE * 4);
  unsigned short* csr    = (unsigned short*)carve((size_t)NB * BSTRIDE * 2);
  int*            bcur   = (int*)carve(512 * 4);
  int2*           rowbe  = (int2*)carve((size_t)N * 8);
  float*          as_    = (float*)carve((size_t)N * 4);
  float*          ad_    = (float*)carve((size_t)N * 4);
  float*          as2_   = (float*)carve((size_t)N * 4);
  float*          ad2_   = (float*)carve((size_t)N * 4);
  int*            flag64 = (int*)carve(256);
  (void)ws_size; (void)in_sizes; (void)n_in; (void)out_size;

  hipMemsetAsync(bcur, 0, 512 * 4, stream);
  detect_idx64_kernel<<<1, 64, 0, stream>>>(ei, flag64);

  // ---- CSR build (one-pass bucketed, XCD-exclusive writes) ----
  bin_edges<<<NBLK_E, 256, 0, stream>>>(ei, flag64, E, bcur, binned);
  place_csr<<<NB, 256, 0, stream>>>(binned, bcur, rowbe, csr, N);

  // ---- weights ----
  prep_weights<<<259, 256, 0, stream>>>(W1, W2, a1_src, a1_dst, a2_src, a2_dst,
                                        Wp1, Wp2, wa);

  const int nb4 = (N + 3) / 4;

  // ---- layer 1: scores from x, aggregate x, GEMM(+bias+ReLU) ----
  alpha1_cast<<<nb4, 256, 0, stream>>>(x, wa, xb, as_, ad_, N);
  gat_aggregate<false, true><<<nb4, 256, 0, stream>>>(rowbe, csr, as_, ad_,
                                                      xb, nullptr, aggx, N);
  {
    dim3 g((N + 63) / 64, HID / 64);
    gemm_mfma<HID, IN, true, false><<<g, 256, 0, stream>>>(
        aggx, Wp1, out1, N, b1, nullptr, nullptr, nullptr, nullptr);
  }

  // ---- layer 2: GEMM (+deterministic fused scores), aggregate ----
  {
    dim3 g((N + 63) / 64, OUT / 64);
    gemm_mfma<OUT, HID, false, true><<<g, 256, 0, stream>>>(
        out1, Wp2, h2, N, nullptr, wa + 256, wa + 512, as2_, ad2_);
  }
  gat_aggregate<true, false><<<nb4, 256, 0, stream>>>(rowbe, csr, as2_,
                                                      ad2_, h2, b2, out, N);
}

// Round 9
// 154.730 us; speedup vs baseline: 24.9006x; 1.1111x over previous
//
#include <hip/hip_runtime.h>
#include <hip/hip_bf16.h>
#include <float.h>
#include <stdint.h>

#define NEG_SLOPE 0.2f

typedef __attribute__((ext_vector_type(8))) short short8;
typedef __attribute__((ext_vector_type(4))) float f32x4;

#define BSTRIDE 3072  // padded per-bucket capacity (mean 2048, 22+ sigma slack)

__device__ inline float b2f(unsigned short u) {
  return __uint_as_float((unsigned int)u << 16);
}
__device__ inline unsigned short f2b(float f) {
  unsigned int u = __float_as_uint(f);
  return (unsigned short)((u + 0x7FFF + ((u >> 16) & 1)) >> 16);
}
__device__ inline float leaky(float e) { return e >= 0.f ? e : NEG_SLOPE * e; }
__device__ inline float blo(unsigned int w) {
  return __uint_as_float(w << 16);
}
__device__ inline float bhi(unsigned int w) {
  return __uint_as_float(w & 0xFFFF0000u);
}

__device__ inline int load_idx(const void* ei, long long pos, int is64) {
  if (is64) return (int)((const long long*)ei)[pos];
  return ((const int*)ei)[pos];
}

// ---------------------------------------------------------------------------
// One-shot prep (replaces detect + memset + prep_weights):
//   blocks [0,128)   : pack W1 -> Wp1 fragment layout
//   blocks [128,256) : pack W2 -> Wp2
//   blocks [256,259) : wa[768] = {W1@a1s, W1@a1d, W2@a2s, W2@a2d}
//   block 259        : zero bcur[512]; detect int64 edge_index (ballot)
// ---------------------------------------------------------------------------
__global__ __launch_bounds__(256) void prep_all(
    const float* __restrict__ W1, const float* __restrict__ W2,
    const float* __restrict__ a1s, const float* __restrict__ a1d,
    const float* __restrict__ a2s, const float* __restrict__ a2d,
    unsigned short* __restrict__ Wp1, unsigned short* __restrict__ Wp2,
    float* __restrict__ wa, int* __restrict__ bcur, const void* __restrict__ ei,
    int* __restrict__ flag64) {
  int b = blockIdx.x;
  int t = threadIdx.x;
  if (b < 128) {
    int i = b * 256 + t;
    int k = i >> 8, n = i & 255;
    Wp1[(((k >> 3) * 256 + n) << 3) + (k & 7)] = f2b(W1[i]);
  } else if (b < 256) {
    int i = (b - 128) * 256 + t;
    int k = i >> 7, n = i & 127;
    Wp2[(((k >> 3) * 128 + n) << 3) + (k & 7)] = f2b(W2[i]);
  } else if (b < 259) {
    int o = (b - 256) * 256 + t;
    float s = 0.f;
    if (o < 128) {
      for (int n = 0; n < 256; ++n) s += W1[o * 256 + n] * a1s[n];
    } else if (o < 256) {
      int k = o - 128;
      for (int n = 0; n < 256; ++n) s += W1[k * 256 + n] * a1d[n];
    } else if (o < 512) {
      int k = o - 256;
      for (int n = 0; n < 128; ++n) s += W2[k * 128 + n] * a2s[n];
    } else {
      int k = o - 512;
      for (int n = 0; n < 128; ++n) s += W2[k * 128 + n] * a2d[n];
    }
    wa[o] = s;
  } else {
    bcur[t] = 0;
    bcur[t + 256] = 0;
    if (t < 64) {
      const int* p = (const int*)ei;
      unsigned long long bl = __ballot(p[2 * t + 1] != 0);
      if (t == 0) *flag64 = (bl == 0ull) ? 1 : 0;
    }
  }
}

// ===========================================================================
// CSR build, one-pass bucketed (bucket = dst>>7; one block owns one bucket's
// csr region => XCD-exclusive writes, no L2 line bouncing).
// ===========================================================================
__global__ __launch_bounds__(256) void bin_edges(
    const void* __restrict__ ei, const int* __restrict__ flag64, int E,
    int* __restrict__ bcursor, unsigned int* __restrict__ binned) {
  __shared__ int hist[512];
  __shared__ int scn[512];
  __shared__ int gb[512];
  __shared__ unsigned int stage[2048];
  int t = threadIdx.x;
  hist[t] = 0; hist[t + 256] = 0;
  __syncthreads();
  const int is64 = *flag64;
  const long long base = (long long)blockIdx.x * 2048;
  const int cblk = (int)min((long long)2048, (long long)E - base);
  int sv[8];
  short bk[8], rk[8];
#pragma unroll
  for (int i = 0; i < 8; ++i) {
    int k = t + i * 256;
    if (k < cblk) {
      long long j = base + k;
      int s = load_idx(ei, j, is64);
      int d = load_idx(ei, (long long)E + j, is64);
      int b = d >> 7;
      bk[i] = (short)b;
      sv[i] = (s << 7) | (d & 127);
      rk[i] = (short)atomicAdd(&hist[b], 1);
    } else {
      bk[i] = -1;
    }
  }
  __syncthreads();
  scn[t] = hist[t]; scn[t + 256] = hist[t + 256];
  __syncthreads();
  for (int off = 1; off < 512; off <<= 1) {
    int v0 = (t >= off) ? scn[t - off] : 0;
    int v1 = scn[t + 256 - off];
    __syncthreads();
    scn[t] += v0;
    scn[t + 256] += v1;
    __syncthreads();
  }
  int c0 = hist[t], c1 = hist[t + 256];
  int l0 = scn[t] - c0, l1 = scn[t + 256] - c1;
  if (c0) gb[t] = atomicAdd(&bcursor[t], c0);
  if (c1) gb[t + 256] = atomicAdd(&bcursor[t + 256], c1);
  scn[t] = l0; scn[t + 256] = l1;
  __syncthreads();
#pragma unroll
  for (int i = 0; i < 8; ++i) {
    if (bk[i] >= 0)
      stage[scn[bk[i]] + rk[i]] = ((unsigned)(int)bk[i] << 23) | (unsigned)sv[i];
  }
  __syncthreads();
#pragma unroll
  for (int i = 0; i < 8; ++i) {
    int k = t + i * 256;
    if (k < cblk) {
      unsigned w = stage[k];
      int b = w >> 23;
      binned[(long long)b * BSTRIDE + gb[b] + (k - scn[b])] = w;
    }
  }
}

__global__ __launch_bounds__(256) void place_csr(
    const unsigned int* __restrict__ binned, const int* __restrict__ bcursor,
    int2* __restrict__ rowbe, unsigned short* __restrict__ csr, int Nn) {
  __shared__ int cnt[128], deg0[128], cur[128];
  int t = threadIdx.x;
  int b = blockIdx.x;
  if (t < 128) cnt[t] = 0;
  __syncthreads();
  const int rbeg = b * BSTRIDE;
  const int rend = rbeg + bcursor[b];
  for (int k = rbeg + t; k < rend; k += 256)
    atomicAdd(&cnt[binned[k] & 127], 1);
  __syncthreads();
  if (t < 128) deg0[t] = cnt[t];
  __syncthreads();
  for (int off = 1; off < 128; off <<= 1) {
    int v = (t >= off && t < 128) ? cnt[t - off] : 0;
    __syncthreads();
    if (t < 128) cnt[t] += v;
    __syncthreads();
  }
  const int node0 = b << 7;
  if (t < 128) {
    int start = rbeg + cnt[t] - deg0[t];
    int node = node0 + t;
    if (node < Nn) rowbe[node] = make_int2(start, start + deg0[t]);
    cur[t] = start;
  }
  __syncthreads();
  for (int k = rbeg + t; k < rend; k += 256) {
    unsigned w = binned[k];
    int pos = atomicAdd(&cur[w & 127], 1);
    csr[pos] = (unsigned short)((w >> 7) & 0xFFFF);
  }
}

// ---------------------------------------------------------------------------
// Layer-1 scores + bf16 cast of x (one wave per node, fp32 x [N,128])
// ---------------------------------------------------------------------------
__global__ __launch_bounds__(256) void alpha1_cast(
    const float* __restrict__ x, const float* __restrict__ wa,
    unsigned short* __restrict__ xb, float* __restrict__ as_out,
    float* __restrict__ ad_out, int Nn) {
  int node = blockIdx.x * 4 + (threadIdx.x >> 6);
  int lane = threadIdx.x & 63;
  if (node >= Nn) return;
  float2 v = *(const float2*)(x + (long long)node * 128 + lane * 2);
  float s1 = v.x * wa[lane * 2] + v.y * wa[lane * 2 + 1];
  float s2 = v.x * wa[128 + lane * 2] + v.y * wa[128 + lane * 2 + 1];
  unsigned int packed = (unsigned int)f2b(v.x) | ((unsigned int)f2b(v.y) << 16);
  *(unsigned int*)(xb + (long long)node * 128 + lane * 2) = packed;
#pragma unroll
  for (int off = 32; off > 0; off >>= 1) {
    s1 += __shfl_down(s1, off);
    s2 += __shfl_down(s2, off);
  }
  if (lane == 0) {
    as_out[node] = s1;
    ad_out[node] = s2;
  }
}

// ---------------------------------------------------------------------------
// MFMA bf16 GEMM, fragments direct from global. Optional bias+ReLU epilogue.
// SCORES (deterministic, atomic-free): per-lane partial dots of A-rows with
// was/wad over K, shfl-reduce across the 4 k-groups, blockIdx.y==0 stores.
// ---------------------------------------------------------------------------
template <int Nn, int Kk, bool BIAS_RELU, bool SCORES>
__global__ __launch_bounds__(256) void gemm_mfma(
    const unsigned short* __restrict__ A, const unsigned short* __restrict__ Bp,
    unsigned short* __restrict__ C, int M, const float* __restrict__ bias,
    const float* __restrict__ was, const float* __restrict__ wad,
    float* __restrict__ s_as, float* __restrict__ s_ad) {
  const int l = threadIdx.x & 63;
  const int wm = threadIdx.x >> 6;
  const int bm = blockIdx.x * 64;
  const int bn = blockIdx.y * 64;
  const int arow = bm + wm * 16 + (l & 15);
  const int kg = l >> 4;

  f32x4 acc[4];
#pragma unroll
  for (int nt = 0; nt < 4; ++nt) acc[nt] = (f32x4){0.f, 0.f, 0.f, 0.f};

  const bool arow_ok = (arow < M);
  const bool do_scores = SCORES && (blockIdx.y == 0);
  float ps = 0.f, pd = 0.f;
#pragma unroll
  for (int kk = 0; kk < Kk; kk += 32) {
    short8 afrag;
    if (arow_ok)
      afrag = *(const short8*)(A + (long long)arow * Kk + kk + kg * 8);
    else
      afrag = (short8){0, 0, 0, 0, 0, 0, 0, 0};
    if (SCORES) {
      if (do_scores) {
        const int kb0 = kk + kg * 8;
#pragma unroll
        for (int i = 0; i < 8; ++i) {
          float v = b2f((unsigned short)afrag[i]);
          ps += v * was[kb0 + i];
          pd += v * wad[kb0 + i];
        }
      }
    }
    const int kb = (kk >> 3) + kg;
#pragma unroll
    for (int nt = 0; nt < 4; ++nt) {
      short8 bfrag = *(const short8*)(Bp + (((long long)kb * Nn + bn + nt * 16 +
                                             (l & 15))
                                            << 3));
      acc[nt] = __builtin_amdgcn_mfma_f32_16x16x32_bf16(afrag, bfrag, acc[nt],
                                                        0, 0, 0);
    }
  }
  if (SCORES) {
    if (do_scores) {
      ps += __shfl_xor(ps, 16); ps += __shfl_xor(ps, 32);
      pd += __shfl_xor(pd, 16); pd += __shfl_xor(pd, 32);
      if (l < 16 && arow_ok) {
        s_as[arow] = ps;
        s_ad[arow] = pd;
      }
    }
  }
#pragma unroll
  for (int nt = 0; nt < 4; ++nt) {
    const int col = bn + nt * 16 + (l & 15);
    float bv = BIAS_RELU ? bias[col] : 0.f;
#pragma unroll
    for (int r = 0; r < 4; ++r) {
      const int row = bm + wm * 16 + (l >> 4) * 4 + r;
      if (row < M) {
        float v = acc[nt][r];
        if (BIAS_RELU) v = fmaxf(v + bv, 0.f);
        C[(long long)row * Nn + col] = f2b(v);
      }
    }
  }
}

// ---------------------------------------------------------------------------
// Single-pass flash-style softmax + gather-aggregate (+ optional bias+ReLU).
// ONE 16-LANE GROUP PER NODE (4 nodes per wave): the group sweeps the node's
// full edge list with unroll-4 (4 independent 256B row loads in flight),
// no cross-group merge shuffles at all. Deferred-max threshold 8.
// ---------------------------------------------------------------------------
template <bool BIAS_RELU, bool OUT_BF16>
__global__ __launch_bounds__(256) void gat_aggregate(
    const int2* __restrict__ rowbe, const unsigned short* __restrict__ csr,
    const float* __restrict__ as, const float* __restrict__ ad,
    const unsigned short* __restrict__ h, const float* __restrict__ bias,
    void* __restrict__ outp, int Nn) {
  constexpr int F = 128;
  const int node = blockIdx.x * 16 + (threadIdx.x >> 4);
  const int hl = threadIdx.x & 15;
  if (node >= Nn) return;
  const int2 be = rowbe[node];
  int t = be.x;
  const int end = be.y;
  const float adn = ad[node];
  const int f0 = hl * 8;

  // self-loop seed
  float m = leaky(as[node] + adn);
  float sg = 1.f;
  float acc[8];
  {
    uint4 w = *(const uint4*)(h + (long long)node * F + f0);
    acc[0] = blo(w.x); acc[1] = bhi(w.x);
    acc[2] = blo(w.y); acc[3] = bhi(w.y);
    acc[4] = blo(w.z); acc[5] = bhi(w.z);
    acc[6] = blo(w.w); acc[7] = bhi(w.w);
  }

  // unroll-4 main loop: batch 4 edges, all 4 row loads issued before use
  for (; t + 4 <= end; t += 4) {
    int s0 = csr[t], s1 = csr[t + 1], s2 = csr[t + 2], s3 = csr[t + 3];
    uint4 w0 = *(const uint4*)(h + (long long)s0 * F + f0);
    uint4 w1 = *(const uint4*)(h + (long long)s1 * F + f0);
    uint4 w2 = *(const uint4*)(h + (long long)s2 * F + f0);
    uint4 w3 = *(const uint4*)(h + (long long)s3 * F + f0);
    float e0 = leaky(as[s0] + adn);
    float e1 = leaky(as[s1] + adn);
    float e2 = leaky(as[s2] + adn);
    float e3 = leaky(as[s3] + adn);
    float em = fmaxf(fmaxf(e0, e1), fmaxf(e2, e3));
    if (em > m + 8.f) {  // deferred-max rescale (rare)
      float sc = __expf(m - em);
      sg *= sc;
#pragma unroll
      for (int j = 0; j < 8; ++j) acc[j] *= sc;
      m = em;
    }
    float p0 = __expf(e0 - m), p1 = __expf(e1 - m);
    float p2 = __expf(e2 - m), p3 = __expf(e3 - m);
    sg += (p0 + p1) + (p2 + p3);
    acc[0] += p0 * blo(w0.x) + p1 * blo(w1.x) + p2 * blo(w2.x) + p3 * blo(w3.x);
    acc[1] += p0 * bhi(w0.x) + p1 * bhi(w1.x) + p2 * bhi(w2.x) + p3 * bhi(w3.x);
    acc[2] += p0 * blo(w0.y) + p1 * blo(w1.y) + p2 * blo(w2.y) + p3 * blo(w3.y);
    acc[3] += p0 * bhi(w0.y) + p1 * bhi(w1.y) + p2 * bhi(w2.y) + p3 * bhi(w3.y);
    acc[4] += p0 * blo(w0.z) + p1 * blo(w1.z) + p2 * blo(w2.z) + p3 * blo(w3.z);
    acc[5] += p0 * bhi(w0.z) + p1 * bhi(w1.z) + p2 * bhi(w2.z) + p3 * bhi(w3.z);
    acc[6] += p0 * blo(w0.w) + p1 * blo(w1.w) + p2 * blo(w2.w) + p3 * blo(w3.w);
    acc[7] += p0 * bhi(w0.w) + p1 * bhi(w1.w) + p2 * bhi(w2.w) + p3 * bhi(w3.w);
  }
  // tail
  for (; t < end; ++t) {
    int s = csr[t];
    uint4 w = *(const uint4*)(h + (long long)s * F + f0);
    float e = leaky(as[s] + adn);
    if (e > m + 8.f) {
      float sc = __expf(m - e);
      sg *= sc;
#pragma unroll
      for (int j = 0; j < 8; ++j) acc[j] *= sc;
      m = e;
    }
    float p = __expf(e - m);
    sg += p;
    acc[0] += p * blo(w.x); acc[1] += p * bhi(w.x);
    acc[2] += p * blo(w.y); acc[3] += p * bhi(w.y);
    acc[4] += p * blo(w.z); acc[5] += p * bhi(w.z);
    acc[6] += p * blo(w.w); acc[7] += p * bhi(w.w);
  }

  const float inv = 1.f / (sg + 1e-16f);
#pragma unroll
  for (int j = 0; j < 8; ++j) {
    acc[j] *= inv;
    if (BIAS_RELU) acc[j] = fmaxf(acc[j] + bias[f0 + j], 0.f);
  }
  if (OUT_BF16) {
    short8 o;
#pragma unroll
    for (int j = 0; j < 8; ++j) o[j] = (short)f2b(acc[j]);
    *(short8*)((unsigned short*)outp + (long long)node * F + f0) = o;
  } else {
    float4 o0 = {acc[0], acc[1], acc[2], acc[3]};
    float4 o1 = {acc[4], acc[5], acc[6], acc[7]};
    float* orow = (float*)outp + (long long)node * F + f0;
    *(float4*)(orow) = o0;
    *(float4*)(orow + 4) = o1;
  }
}

extern "C" void kernel_launch(void* const* d_in, const int* in_sizes, int n_in,
                              void* d_out, int out_size, void* d_ws,
                              size_t ws_size, hipStream_t stream) {
  const float* x      = (const float*)d_in[0];
  const void*  ei     = d_in[1];
  const float* W1     = (const float*)d_in[2];
  const float* a1_src = (const float*)d_in[3];
  const float* a1_dst = (const float*)d_in[4];
  const float* b1     = (const float*)d_in[5];
  const float* W2     = (const float*)d_in[6];
  const float* a2_src = (const float*)d_in[7];
  const float* a2_dst = (const float*)d_in[8];
  const float* b2     = (const float*)d_in[9];
  float* out = (float*)d_out;

  const int N = 50000, E = 800000, IN = 128, HID = 256, OUT = 128;
  const int NBLK_E = (E + 2047) / 2048;
  const int NB = (N + 127) >> 7;

  char* ws = (char*)d_ws;
  size_t off = 0;
  auto carve = [&](size_t bytes) -> void* {
    void* p = ws + off;
    off = (off + bytes + 255) & ~(size_t)255;
    return p;
  };
  unsigned short* xb     = (unsigned short*)carve((size_t)N * IN * 2);
  unsigned short* aggx   = (unsigned short*)carve((size_t)N * IN * 2);
  unsigned short* out1   = (unsigned short*)carve((size_t)N * HID * 2);
  unsigned short* h2     = (unsigned short*)carve((size_t)N * OUT * 2);
  unsigned short* Wp1    = (unsigned short*)carve((size_t)IN * HID * 2);
  unsigned short* Wp2    = (unsigned short*)carve((size_t)HID * OUT * 2);
  float*          wa     = (float*)carve(768 * 4);
  unsigned int*   binned = (unsigned int*)carve((size_t)NB * BSTRIDE * 4);
  unsigned short* csr    = (unsigned short*)carve((size_t)NB * BSTRIDE * 2);
  int*            bcur   = (int*)carve(512 * 4);
  int2*           rowbe  = (int2*)carve((size_t)N * 8);
  float*          as_    = (float*)carve((size_t)N * 4);
  float*          ad_    = (float*)carve((size_t)N * 4);
  float*          as2_   = (float*)carve((size_t)N * 4);
  float*          ad2_   = (float*)carve((size_t)N * 4);
  int*            flag64 = (int*)carve(256);
  (void)ws_size; (void)in_sizes; (void)n_in; (void)out_size;

  // ---- prep (weights pack + matvecs + bcur zero + idx64 detect) ----
  prep_all<<<260, 256, 0, stream>>>(W1, W2, a1_src, a1_dst, a2_src, a2_dst,
                                    Wp1, Wp2, wa, bcur, ei, flag64);

  // ---- CSR build (one-pass bucketed, XCD-exclusive writes) ----
  bin_edges<<<NBLK_E, 256, 0, stream>>>(ei, flag64, E, bcur, binned);
  place_csr<<<NB, 256, 0, stream>>>(binned, bcur, rowbe, csr, N);

  const int nb4 = (N + 3) / 4;
  const int nb16 = (N + 15) / 16;

  // ---- layer 1: scores from x, aggregate x, GEMM(+bias+ReLU) ----
  alpha1_cast<<<nb4, 256, 0, stream>>>(x, wa, xb, as_, ad_, N);
  gat_aggregate<false, true><<<nb16, 256, 0, stream>>>(rowbe, csr, as_, ad_,
                                                       xb, nullptr, aggx, N);
  {
    dim3 g((N + 63) / 64, HID / 64);
    gemm_mfma<HID, IN, true, false><<<g, 256, 0, stream>>>(
        aggx, Wp1, out1, N, b1, nullptr, nullptr, nullptr, nullptr);
  }

  // ---- layer 2: GEMM (+deterministic fused scores), aggregate ----
  {
    dim3 g((N + 63) / 64, OUT / 64);
    gemm_mfma<OUT, HID, false, true><<<g, 256, 0, stream>>>(
        out1, Wp2, h2, N, nullptr, wa + 256, wa + 512, as2_, ad2_);
  }
  gat_aggregate<true, false><<<nb16, 256, 0, stream>>>(rowbe, csr, as2_,
                                                       ad2_, h2, b2, out, N);
}

// Round 10
// 151.170 us; speedup vs baseline: 25.4870x; 1.0236x over previous
//
#include <hip/hip_runtime.h>
#include <hip/hip_bf16.h>
#include <float.h>
#include <stdint.h>

#define NEG_SLOPE 0.2f

typedef __attribute__((ext_vector_type(8))) short short8;
typedef __attribute__((ext_vector_type(4))) float f32x4;

#define BSTRIDE 3584  // padded per-bucket capacity (mean 2046 + node-pad <=896)

__device__ inline float b2f(unsigned short u) {
  return __uint_as_float((unsigned int)u << 16);
}
__device__ inline unsigned short f2b(float f) {
  unsigned int u = __float_as_uint(f);
  return (unsigned short)((u + 0x7FFF + ((u >> 16) & 1)) >> 16);
}
__device__ inline float leaky(float e) { return e >= 0.f ? e : NEG_SLOPE * e; }
__device__ inline float blo(unsigned int w) {
  return __uint_as_float(w << 16);
}
__device__ inline float bhi(unsigned int w) {
  return __uint_as_float(w & 0xFFFF0000u);
}

__device__ inline int load_idx(const void* ei, long long pos, int is64) {
  if (is64) return (int)((const long long*)ei)[pos];
  return ((const int*)ei)[pos];
}

// ---------------------------------------------------------------------------
// One-shot prep:
//   blocks [0,128)   : pack W1 -> Wp1 fragment layout
//   blocks [128,256) : pack W2 -> Wp2
//   blocks [256,259) : wa[768] = {W1@a1s, W1@a1d, W2@a2s, W2@a2d}
//   block 259        : zero bcur[512]; detect int64 edge_index (ballot)
// ---------------------------------------------------------------------------
__global__ __launch_bounds__(256) void prep_all(
    const float* __restrict__ W1, const float* __restrict__ W2,
    const float* __restrict__ a1s, const float* __restrict__ a1d,
    const float* __restrict__ a2s, const float* __restrict__ a2d,
    unsigned short* __restrict__ Wp1, unsigned short* __restrict__ Wp2,
    float* __restrict__ wa, int* __restrict__ bcur, const void* __restrict__ ei,
    int* __restrict__ flag64) {
  int b = blockIdx.x;
  int t = threadIdx.x;
  if (b < 128) {
    int i = b * 256 + t;
    int k = i >> 8, n = i & 255;
    Wp1[(((k >> 3) * 256 + n) << 3) + (k & 7)] = f2b(W1[i]);
  } else if (b < 256) {
    int i = (b - 128) * 256 + t;
    int k = i >> 7, n = i & 127;
    Wp2[(((k >> 3) * 128 + n) << 3) + (k & 7)] = f2b(W2[i]);
  } else if (b < 259) {
    int o = (b - 256) * 256 + t;
    float s = 0.f;
    if (o < 128) {
      for (int n = 0; n < 256; ++n) s += W1[o * 256 + n] * a1s[n];
    } else if (o < 256) {
      int k = o - 128;
      for (int n = 0; n < 256; ++n) s += W1[k * 256 + n] * a1d[n];
    } else if (o < 512) {
      int k = o - 256;
      for (int n = 0; n < 128; ++n) s += W2[k * 128 + n] * a2s[n];
    } else {
      int k = o - 512;
      for (int n = 0; n < 128; ++n) s += W2[k * 128 + n] * a2d[n];
    }
    wa[o] = s;
  } else {
    bcur[t] = 0;
    bcur[t + 256] = 0;
    if (t < 64) {
      const int* p = (const int*)ei;
      unsigned long long bl = __ballot(p[2 * t + 1] != 0);
      if (t == 0) *flag64 = (bl == 0ull) ? 1 : 0;
    }
  }
}

// ===========================================================================
// Fused dispatch: blocks [0,nblk) bin edges into bucket regions (bucket =
// dst>>7, XCD-exclusive downstream writes); blocks [nblk, nblk+nb4) compute
// layer-1 scores + bf16 cast of x. Independent work, one launch.
// ===========================================================================
__global__ __launch_bounds__(256) void bin_and_alpha(
    const void* __restrict__ ei, const int* __restrict__ flag64, int E,
    int* __restrict__ bcursor, unsigned int* __restrict__ binned, int nblk,
    const float* __restrict__ x, const float* __restrict__ wa,
    unsigned short* __restrict__ xb, float* __restrict__ as_out,
    float* __restrict__ ad_out, int Nn) {
  __shared__ int hist[512];
  __shared__ int scn[512];
  __shared__ int gb[512];
  __shared__ unsigned int stage[2048];
  int t = threadIdx.x;
  if (blockIdx.x >= nblk) {
    // ---- alpha1 + cast part ----
    int node = (blockIdx.x - nblk) * 4 + (t >> 6);
    int lane = t & 63;
    if (node >= Nn) return;
    float2 v = *(const float2*)(x + (long long)node * 128 + lane * 2);
    float s1 = v.x * wa[lane * 2] + v.y * wa[lane * 2 + 1];
    float s2 = v.x * wa[128 + lane * 2] + v.y * wa[128 + lane * 2 + 1];
    unsigned int packed =
        (unsigned int)f2b(v.x) | ((unsigned int)f2b(v.y) << 16);
    *(unsigned int*)(xb + (long long)node * 128 + lane * 2) = packed;
#pragma unroll
    for (int off = 32; off > 0; off >>= 1) {
      s1 += __shfl_down(s1, off);
      s2 += __shfl_down(s2, off);
    }
    if (lane == 0) {
      as_out[node] = s1;
      ad_out[node] = s2;
    }
    return;
  }
  // ---- bin_edges part ----
  hist[t] = 0; hist[t + 256] = 0;
  __syncthreads();
  const int is64 = *flag64;
  const long long base = (long long)blockIdx.x * 2048;
  const int cblk = (int)min((long long)2048, (long long)E - base);
  int sv[8];
  short bk[8], rk[8];
#pragma unroll
  for (int i = 0; i < 8; ++i) {
    int k = t + i * 256;
    if (k < cblk) {
      long long j = base + k;
      int s = load_idx(ei, j, is64);
      int d = load_idx(ei, (long long)E + j, is64);
      int b = d >> 7;
      bk[i] = (short)b;
      sv[i] = (s << 7) | (d & 127);
      rk[i] = (short)atomicAdd(&hist[b], 1);
    } else {
      bk[i] = -1;
    }
  }
  __syncthreads();
  scn[t] = hist[t]; scn[t + 256] = hist[t + 256];
  __syncthreads();
  for (int off = 1; off < 512; off <<= 1) {
    int v0 = (t >= off) ? scn[t - off] : 0;
    int v1 = scn[t + 256 - off];
    __syncthreads();
    scn[t] += v0;
    scn[t + 256] += v1;
    __syncthreads();
  }
  int c0 = hist[t], c1 = hist[t + 256];
  int l0 = scn[t] - c0, l1 = scn[t + 256] - c1;
  if (c0) gb[t] = atomicAdd(&bcursor[t], c0);
  if (c1) gb[t + 256] = atomicAdd(&bcursor[t + 256], c1);
  scn[t] = l0; scn[t + 256] = l1;
  __syncthreads();
#pragma unroll
  for (int i = 0; i < 8; ++i) {
    if (bk[i] >= 0)
      stage[scn[bk[i]] + rk[i]] = ((unsigned)(int)bk[i] << 23) | (unsigned)sv[i];
  }
  __syncthreads();
#pragma unroll
  for (int i = 0; i < 8; ++i) {
    int k = t + i * 256;
    if (k < cblk) {
      unsigned w = stage[k];
      int b = w >> 23;
      binned[(long long)b * BSTRIDE + gb[b] + (k - scn[b])] = w;
    }
  }
}

// ---------------------------------------------------------------------------
// place_csr: one block per bucket. Per-node degree + LDS scan with each
// node's csr segment start aligned to 8 entries (16B); pad slots zeroed so
// the aggregate can read whole uint4 index groups safely.
// ---------------------------------------------------------------------------
__global__ __launch_bounds__(256) void place_csr(
    const unsigned int* __restrict__ binned, const int* __restrict__ bcursor,
    int2* __restrict__ rowbe, unsigned short* __restrict__ csr, int Nn) {
  __shared__ int cnt[128], deg0[128], cur[128], alc[128];
  int t = threadIdx.x;
  int b = blockIdx.x;
  if (t < 128) cnt[t] = 0;
  __syncthreads();
  const int rbeg = b * BSTRIDE;
  const int rend = rbeg + bcursor[b];
  for (int k = rbeg + t; k < rend; k += 256)
    atomicAdd(&cnt[binned[k] & 127], 1);
  __syncthreads();
  if (t < 128) {
    deg0[t] = cnt[t];
    alc[t] = (cnt[t] + 7) & ~7;  // 8-aligned allocation
    cnt[t] = alc[t];
  }
  __syncthreads();
  for (int off = 1; off < 128; off <<= 1) {
    int v = (t >= off && t < 128) ? cnt[t - off] : 0;
    __syncthreads();
    if (t < 128) cnt[t] += v;
    __syncthreads();
  }
  const int node0 = b << 7;
  if (t < 128) {
    int start = rbeg + cnt[t] - alc[t];
    int node = node0 + t;
    if (node < Nn) rowbe[node] = make_int2(start, start + deg0[t]);
    cur[t] = start;
  }
  __syncthreads();
  for (int k = rbeg + t; k < rend; k += 256) {
    unsigned w = binned[k];
    int pos = atomicAdd(&cur[w & 127], 1);
    csr[pos] = (unsigned short)((w >> 7) & 0xFFFF);
  }
  __syncthreads();
  if (t < 128 && (node0 + t) < Nn) {
    int s0 = cur[t];          // start + deg
    int s1 = rbeg + cnt[t];   // start + alloc
    for (int k = s0; k < s1; ++k) csr[k] = 0;  // zero pads (masked in agg)
  }
}

// ---------------------------------------------------------------------------
// MFMA bf16 GEMM, fragments direct from global. Optional bias+ReLU epilogue.
// SCORES (deterministic, atomic-free): per-lane partial dots of A-rows with
// was/wad over K, shfl-reduce across the 4 k-groups, blockIdx.y==0 stores.
// ---------------------------------------------------------------------------
template <int Nn, int Kk, bool BIAS_RELU, bool SCORES>
__global__ __launch_bounds__(256) void gemm_mfma(
    const unsigned short* __restrict__ A, const unsigned short* __restrict__ Bp,
    unsigned short* __restrict__ C, int M, const float* __restrict__ bias,
    const float* __restrict__ was, const float* __restrict__ wad,
    float* __restrict__ s_as, float* __restrict__ s_ad) {
  const int l = threadIdx.x & 63;
  const int wm = threadIdx.x >> 6;
  const int bm = blockIdx.x * 64;
  const int bn = blockIdx.y * 64;
  const int arow = bm + wm * 16 + (l & 15);
  const int kg = l >> 4;

  f32x4 acc[4];
#pragma unroll
  for (int nt = 0; nt < 4; ++nt) acc[nt] = (f32x4){0.f, 0.f, 0.f, 0.f};

  const bool arow_ok = (arow < M);
  const bool do_scores = SCORES && (blockIdx.y == 0);
  float ps = 0.f, pd = 0.f;
#pragma unroll
  for (int kk = 0; kk < Kk; kk += 32) {
    short8 afrag;
    if (arow_ok)
      afrag = *(const short8*)(A + (long long)arow * Kk + kk + kg * 8);
    else
      afrag = (short8){0, 0, 0, 0, 0, 0, 0, 0};
    if (SCORES) {
      if (do_scores) {
        const int kb0 = kk + kg * 8;
#pragma unroll
        for (int i = 0; i < 8; ++i) {
          float v = b2f((unsigned short)afrag[i]);
          ps += v * was[kb0 + i];
          pd += v * wad[kb0 + i];
        }
      }
    }
    const int kb = (kk >> 3) + kg;
#pragma unroll
    for (int nt = 0; nt < 4; ++nt) {
      short8 bfrag = *(const short8*)(Bp + (((long long)kb * Nn + bn + nt * 16 +
                                             (l & 15))
                                            << 3));
      acc[nt] = __builtin_amdgcn_mfma_f32_16x16x32_bf16(afrag, bfrag, acc[nt],
                                                        0, 0, 0);
    }
  }
  if (SCORES) {
    if (do_scores) {
      ps += __shfl_xor(ps, 16); ps += __shfl_xor(ps, 32);
      pd += __shfl_xor(pd, 16); pd += __shfl_xor(pd, 32);
      if (l < 16 && arow_ok) {
        s_as[arow] = ps;
        s_ad[arow] = pd;
      }
    }
  }
#pragma unroll
  for (int nt = 0; nt < 4; ++nt) {
    const int col = bn + nt * 16 + (l & 15);
    float bv = BIAS_RELU ? bias[col] : 0.f;
#pragma unroll
    for (int r = 0; r < 4; ++r) {
      const int row = bm + wm * 16 + (l >> 4) * 4 + r;
      if (row < M) {
        float v = acc[nt][r];
        if (BIAS_RELU) v = fmaxf(v + bv, 0.f);
        C[(long long)row * Nn + col] = f2b(v);
      }
    }
  }
}

// ---------------------------------------------------------------------------
// Single-pass flash-style softmax + gather-aggregate. One 16-lane group per
// node. Index stream read as uint4 (8 edges per load, segment 8-aligned with
// zeroed pads). Unroll-8 body: 8 independent 256B row loads in flight.
// Masked final iteration (e=-inf => p=0 for pad slots). Deferred-max thr 8.
// ---------------------------------------------------------------------------
template <bool BIAS_RELU, bool OUT_BF16>
__global__ __launch_bounds__(256) void gat_aggregate(
    const int2* __restrict__ rowbe, const unsigned short* __restrict__ csr,
    const float* __restrict__ as, const float* __restrict__ ad,
    const unsigned short* __restrict__ h, const float* __restrict__ bias,
    void* __restrict__ outp, int Nn) {
  constexpr int F = 128;
  const int node = blockIdx.x * 16 + (threadIdx.x >> 4);
  const int hl = threadIdx.x & 15;
  if (node >= Nn) return;
  const int2 be = rowbe[node];
  const int beg = be.x, end = be.y;
  const float adn = ad[node];
  const int f0 = hl * 8;

  // self-loop seed
  float m = leaky(as[node] + adn);
  float sg = 1.f;
  float acc[8];
  {
    uint4 w = *(const uint4*)(h + (long long)node * F + f0);
    acc[0] = blo(w.x); acc[1] = bhi(w.x);
    acc[2] = blo(w.y); acc[3] = bhi(w.y);
    acc[4] = blo(w.z); acc[5] = bhi(w.z);
    acc[6] = blo(w.w); acc[7] = bhi(w.w);
  }

  int t = beg;
  // full unroll-8 iterations
  for (; t + 8 <= end; t += 8) {
    uint4 c = *(const uint4*)(csr + t);
    int s[8];
    s[0] = c.x & 0xFFFF; s[1] = c.x >> 16;
    s[2] = c.y & 0xFFFF; s[3] = c.y >> 16;
    s[4] = c.z & 0xFFFF; s[5] = c.z >> 16;
    s[6] = c.w & 0xFFFF; s[7] = c.w >> 16;
    uint4 w[8];
#pragma unroll
    for (int i = 0; i < 8; ++i)
      w[i] = *(const uint4*)(h + (long long)s[i] * F + f0);
    float e[8];
#pragma unroll
    for (int i = 0; i < 8; ++i) e[i] = leaky(as[s[i]] + adn);
    float em = e[0];
#pragma unroll
    for (int i = 1; i < 8; ++i) em = fmaxf(em, e[i]);
    if (em > m + 8.f) {
      float sc = __expf(m - em);
      sg *= sc;
#pragma unroll
      for (int j = 0; j < 8; ++j) acc[j] *= sc;
      m = em;
    }
    float p[8];
#pragma unroll
    for (int i = 0; i < 8; ++i) p[i] = __expf(e[i] - m);
#pragma unroll
    for (int i = 0; i < 8; ++i) sg += p[i];
#pragma unroll
    for (int i = 0; i < 8; ++i) {
      acc[0] += p[i] * blo(w[i].x); acc[1] += p[i] * bhi(w[i].x);
      acc[2] += p[i] * blo(w[i].y); acc[3] += p[i] * bhi(w[i].y);
      acc[4] += p[i] * blo(w[i].z); acc[5] += p[i] * bhi(w[i].z);
      acc[6] += p[i] * blo(w[i].w); acc[7] += p[i] * bhi(w[i].w);
    }
  }
  // masked final iteration (pads are zeroed indices; e forced to -inf)
  if (t < end) {
    uint4 c = *(const uint4*)(csr + t);
    int s[8];
    s[0] = c.x & 0xFFFF; s[1] = c.x >> 16;
    s[2] = c.y & 0xFFFF; s[3] = c.y >> 16;
    s[4] = c.z & 0xFFFF; s[5] = c.z >> 16;
    s[6] = c.w & 0xFFFF; s[7] = c.w >> 16;
    uint4 w[8];
#pragma unroll
    for (int i = 0; i < 8; ++i)
      w[i] = *(const uint4*)(h + (long long)s[i] * F + f0);
    float e[8];
#pragma unroll
    for (int i = 0; i < 8; ++i)
      e[i] = (t + i < end) ? leaky(as[s[i]] + adn) : -3.4e38f;
    float em = e[0];
#pragma unroll
    for (int i = 1; i < 8; ++i) em = fmaxf(em, e[i]);
    if (em > m + 8.f) {
      float sc = __expf(m - em);
      sg *= sc;
#pragma unroll
      for (int j = 0; j < 8; ++j) acc[j] *= sc;
      m = em;
    }
    float p[8];
#pragma unroll
    for (int i = 0; i < 8; ++i) p[i] = __expf(e[i] - m);
#pragma unroll
    for (int i = 0; i < 8; ++i) sg += p[i];
#pragma unroll
    for (int i = 0; i < 8; ++i) {
      acc[0] += p[i] * blo(w[i].x); acc[1] += p[i] * bhi(w[i].x);
      acc[2] += p[i] * blo(w[i].y); acc[3] += p[i] * bhi(w[i].y);
      acc[4] += p[i] * blo(w[i].z); acc[5] += p[i] * bhi(w[i].z);
      acc[6] += p[i] * blo(w[i].w); acc[7] += p[i] * bhi(w[i].w);
    }
  }

  const float inv = 1.f / (sg + 1e-16f);
#pragma unroll
  for (int j = 0; j < 8; ++j) {
    acc[j] *= inv;
    if (BIAS_RELU) acc[j] = fmaxf(acc[j] + bias[f0 + j], 0.f);
  }
  if (OUT_BF16) {
    short8 o;
#pragma unroll
    for (int j = 0; j < 8; ++j) o[j] = (short)f2b(acc[j]);
    *(short8*)((unsigned short*)outp + (long long)node * F + f0) = o;
  } else {
    float4 o0 = {acc[0], acc[1], acc[2], acc[3]};
    float4 o1 = {acc[4], acc[5], acc[6], acc[7]};
    float* orow = (float*)outp + (long long)node * F + f0;
    *(float4*)(orow) = o0;
    *(float4*)(orow + 4) = o1;
  }
}

extern "C" void kernel_launch(void* const* d_in, const int* in_sizes, int n_in,
                              void* d_out, int out_size, void* d_ws,
                              size_t ws_size, hipStream_t stream) {
  const float* x      = (const float*)d_in[0];
  const void*  ei     = d_in[1];
  const float* W1     = (const float*)d_in[2];
  const float* a1_src = (const float*)d_in[3];
  const float* a1_dst = (const float*)d_in[4];
  const float* b1     = (const float*)d_in[5];
  const float* W2     = (const float*)d_in[6];
  const float* a2_src = (const float*)d_in[7];
  const float* a2_dst = (const float*)d_in[8];
  const float* b2     = (const float*)d_in[9];
  float* out = (float*)d_out;

  const int N = 50000, E = 800000, IN = 128, HID = 256, OUT = 128;
  const int NBLK_E = (E + 2047) / 2048;
  const int NB = (N + 127) >> 7;
  const int nb4 = (N + 3) / 4;
  const int nb16 = (N + 15) / 16;

  char* ws = (char*)d_ws;
  size_t off = 0;
  auto carve = [&](size_t bytes) -> void* {
    void* p = ws + off;
    off = (off + bytes + 255) & ~(size_t)255;
    return p;
  };
  unsigned short* xb     = (unsigned short*)carve((size_t)N * IN * 2);
  unsigned short* aggx   = (unsigned short*)carve((size_t)N * IN * 2);
  unsigned short* out1   = (unsigned short*)carve((size_t)N * HID * 2);
  unsigned short* h2     = (unsigned short*)carve((size_t)N * OUT * 2);
  unsigned short* Wp1    = (unsigned short*)carve((size_t)IN * HID * 2);
  unsigned short* Wp2    = (unsigned short*)carve((size_t)HID * OUT * 2);
  float*          wa     = (float*)carve(768 * 4);
  unsigned int*   binned = (unsigned int*)carve((size_t)NB * BSTRIDE * 4);
  unsigned short* csr    = (unsigned short*)carve((size_t)NB * BSTRIDE * 2);
  int*            bcur   = (int*)carve(512 * 4);
  int2*           rowbe  = (int2*)carve((size_t)N * 8);
  float*          as_    = (float*)carve((size_t)N * 4);
  float*          ad_    = (float*)carve((size_t)N * 4);
  float*          as2_   = (float*)carve((size_t)N * 4);
  float*          ad2_   = (float*)carve((size_t)N * 4);
  int*            flag64 = (int*)carve(256);
  (void)ws_size; (void)in_sizes; (void)n_in; (void)out_size;

  // ---- prep (weights pack + matvecs + bcur zero + idx64 detect) ----
  prep_all<<<260, 256, 0, stream>>>(W1, W2, a1_src, a1_dst, a2_src, a2_dst,
                                    Wp1, Wp2, wa, bcur, ei, flag64);

  // ---- fused: edge binning + layer-1 scores/cast ----
  bin_and_alpha<<<NBLK_E + nb4, 256, 0, stream>>>(
      ei, flag64, E, bcur, binned, NBLK_E, x, wa, xb, as_, ad_, N);

  // ---- CSR finalize (8-aligned, zero-padded segments) ----
  place_csr<<<NB, 256, 0, stream>>>(binned, bcur, rowbe, csr, N);

  // ---- layer 1: aggregate x, GEMM(+bias+ReLU) ----
  gat_aggregate<false, true><<<nb16, 256, 0, stream>>>(rowbe, csr, as_, ad_,
                                                       xb, nullptr, aggx, N);
  {
    dim3 g((N + 63) / 64, HID / 64);
    gemm_mfma<HID, IN, true, false><<<g, 256, 0, stream>>>(
        aggx, Wp1, out1, N, b1, nullptr, nullptr, nullptr, nullptr);
  }

  // ---- layer 2: GEMM (+deterministic fused scores), aggregate ----
  {
    dim3 g((N + 63) / 64, OUT / 64);
    gemm_mfma<OUT, HID, false, true><<<g, 256, 0, stream>>>(
        out1, Wp2, h2, N, nullptr, wa + 256, wa + 512, as2_, ad2_);
  }
  gat_aggregate<true, false><<<nb16, 256, 0, stream>>>(rowbe, csr, as2_,
                                                       ad2_, h2, b2, out, N);
}